// Round 3
// baseline (308.061 us; speedup 1.0000x reference)
//
#include <hip/hip_runtime.h>

#define BQ 2048
#define MM 65536
#define CC 128
#define NSPLIT 32
#define KCHUNK (MM/NSPLIT)
#define NQB (BQ/64)
#define NBUCKET 1024
#define NTILES (MM/64)

typedef short short8 __attribute__((ext_vector_type(8)));
typedef float f32x4 __attribute__((ext_vector_type(4)));

__device__ __forceinline__ unsigned short f2bf(float x) {
    unsigned int u = __builtin_bit_cast(unsigned int, x);
    u = (u + 0x7FFFu + ((u >> 16) & 1u)) >> 16;
    return (unsigned short)u;
}
__device__ __forceinline__ float bf2f(unsigned short u) {
    return __builtin_bit_cast(float, (unsigned int)u << 16);
}
__device__ __forceinline__ int bucket_of(float v) {
    return (int)fminf(fmaxf(v * 1024.0f, 0.0f), 1023.0f);
}

// ---------------- const prep: G = Kw@Kw^T, kb2 = key_b@Kw^T, etab = y_emb@W3 + msg_b ----
__global__ __launch_bounds__(128) void prep_const_kernel(
    const float* __restrict__ keyw, const float* __restrict__ keyb,
    const float* __restrict__ msgw, const float* __restrict__ msgb,
    const float* __restrict__ yemb,
    float* __restrict__ G, float* __restrict__ kb2, float* __restrict__ etab)
{
    __shared__ float rowd[128];
    int t = threadIdx.x;
    int d = blockIdx.x;
    if (d < 128) {
        rowd[t] = keyw[d*128 + t];
        __syncthreads();
        float acc = 0.f;
        for (int c2 = 0; c2 < 128; ++c2) acc = fmaf(rowd[c2], keyw[t*128 + c2], acc);
        G[d*128 + t] = acc;
    } else if (d == 128) {
        rowd[t] = keyb[t];
        __syncthreads();
        float acc = 0.f;
        for (int c2 = 0; c2 < 128; ++c2) acc = fmaf(rowd[c2], keyw[t*128 + c2], acc);
        kb2[t] = acc;
    } else {
        float acc0 = msgb[t], acc1 = msgb[t];
        for (int c2 = 0; c2 < 128; ++c2) {
            float w3 = msgw[(256 + c2)*128 + t];
            acc0 = fmaf(yemb[c2], w3, acc0);
            acc1 = fmaf(yemb[128 + c2], w3, acc1);
        }
        etab[t] = acc0;
        etab[128 + t] = acc1;
    }
}

// ---------------- deterministic counting sort of memory keys by mst -------------------
__global__ __launch_bounds__(256) void sort_hist_kernel(
    const float* __restrict__ mst, unsigned int* __restrict__ hist)
{
    __shared__ unsigned int h[NBUCKET];
    int t = threadIdx.x, b = blockIdx.x;
    #pragma unroll
    for (int j = t; j < NBUCKET; j += 256) h[j] = 0;
    __syncthreads();
    int bin = bucket_of(mst[b*256 + t]);
    atomicAdd(&h[bin], 1u);
    __syncthreads();
    #pragma unroll
    for (int j = t; j < NBUCKET; j += 256) hist[(size_t)b*NBUCKET + j] = h[j];
}

__global__ __launch_bounds__(1024) void sort_scan_kernel(
    unsigned int* __restrict__ hist, unsigned int* __restrict__ gbase)
{
    __shared__ unsigned int tot[NBUCKET];
    __shared__ unsigned int sc[NBUCKET];
    int j = threadIdx.x;
    unsigned int run = 0;
    for (int b = 0; b < 256; ++b) {
        unsigned int v = hist[(size_t)b*NBUCKET + j];
        hist[(size_t)b*NBUCKET + j] = run;
        run += v;
    }
    tot[j] = run;
    sc[j] = run;
    __syncthreads();
    for (int off = 1; off < NBUCKET; off <<= 1) {
        unsigned int y = (j >= off) ? sc[j - off] : 0u;
        __syncthreads();
        sc[j] += y;
        __syncthreads();
    }
    gbase[j] = sc[j] - tot[j];   // exclusive
}

__global__ __launch_bounds__(256) void sort_scatter_kernel(
    const float* __restrict__ mst, const unsigned int* __restrict__ hist,
    const unsigned int* __restrict__ gbase,
    int* __restrict__ dperm, float* __restrict__ mst_s)
{
    __shared__ int bins[256];
    int t = threadIdx.x, b = blockIdx.x;
    int i = b*256 + t;
    float v = mst[i];
    int bin = bucket_of(v);
    bins[t] = bin;
    __syncthreads();
    int pos = 0;
    for (int j = 0; j < t; ++j) pos += (bins[j] == bin);
    unsigned int dest = gbase[bin] + hist[(size_t)b*NBUCKET + bin] + pos;
    dperm[dest] = i;
    mst_s[dest] = v;
}

__global__ __launch_bounds__(1024) void tilemin_kernel(
    const float* __restrict__ mst_s, float* __restrict__ tilemin)
{
    int t = threadIdx.x;   // one tile per thread, NTILES=1024
    float m = 3.0e38f;
    const float4* p = (const float4*)(mst_s + t*64);
    #pragma unroll
    for (int j = 0; j < 16; ++j) {
        float4 v = p[j];
        m = fminf(m, fminf(fminf(v.x, v.y), fminf(v.z, v.w)));
    }
    tilemin[t] = m;
}

// ---------------- exact query rank by seed_time (deterministic) -----------------------
__global__ __launch_bounds__(256) void qrank_kernel(
    const float* __restrict__ seed, int* __restrict__ qperm,
    int* __restrict__ qrank, float* __restrict__ seed_s)
{
    __shared__ float sl[256];
    int q = blockIdx.x*256 + threadIdx.x;
    float v = seed[q];
    int r = 0;
    for (int t0 = 0; t0 < BQ; t0 += 256) {
        sl[threadIdx.x] = seed[t0 + threadIdx.x];
        __syncthreads();
        for (int j = 0; j < 256; ++j) {
            float u = sl[j];
            int gj = t0 + j;
            r += (u < v) || (u == v && gj < q);
        }
        __syncthreads();
    }
    qperm[r] = q;
    qrank[q] = r;
    seed_s[r] = v;
}

// ---------------- memory l2norm (gathered via dperm) -> xhat + xhatT + y_s -------------
__global__ __launch_bounds__(256) void mem_norm_kernel(
    const float* __restrict__ mx, const int* __restrict__ dperm,
    const int* __restrict__ memy,
    unsigned short* __restrict__ xhat, unsigned short* __restrict__ xhatT,
    float* __restrict__ y_s)
{
    __shared__ __align__(16) float tile[64*132];
    __shared__ float rs[64];
    __shared__ float invn[64];
    __shared__ int operm[64];
    const int t = threadIdx.x;
    const int lane = t & 63;
    const int kb0 = blockIdx.x * 64;

    if (t < 64) operm[t] = dperm[kb0 + t];
    __syncthreads();
    if (t < 64) y_s[kb0 + t] = (float)memy[operm[t]];

    float4 vals[8];
    int rows[8];
    #pragma unroll
    for (int i = 0; i < 8; ++i) {
        int idx = t + 256*i;            // float4 id 0..2047
        int e = idx * 4;
        int row = e >> 7, col = e & 127;
        float4 v = *(const float4*)(mx + (size_t)operm[row]*CC + col);
        vals[i] = v; rows[i] = row;
        *(float4*)&tile[row*132 + col] = v;
        float s = v.x*v.x + v.y*v.y + v.z*v.z + v.w*v.w;
        #pragma unroll
        for (int m2 = 1; m2 < 32; m2 <<= 1) s += __shfl_xor(s, m2, 64);
        if ((lane & 31) == 0) rs[row] = s;
    }
    __syncthreads();
    if (t < 64) invn[t] = 1.0f / fmaxf(sqrtf(rs[t]), 1e-12f);
    __syncthreads();
    #pragma unroll
    for (int i = 0; i < 8; ++i) {
        float sc = invn[rows[i]];
        float4 v = vals[i];
        ushort4 o;
        o.x = f2bf(v.x*sc); o.y = f2bf(v.y*sc); o.z = f2bf(v.z*sc); o.w = f2bf(v.w*sc);
        int idx = t + 256*i;
        *(ushort4*)(xhat + (size_t)kb0*CC + idx*4) = o;
    }
    {
        int c = t >> 1, h = t & 1;
        #pragma unroll
        for (int seg = 0; seg < 4; ++seg) {
            unsigned int pk[4];
            #pragma unroll
            for (int j = 0; j < 4; ++j) {
                int k0 = h*32 + seg*8 + j*2;
                unsigned int lo = f2bf(tile[k0*132 + c] * invn[k0]);
                unsigned int hi = f2bf(tile[(k0+1)*132 + c] * invn[k0+1]);
                pk[j] = lo | (hi << 16);
            }
            uint4 v; v.x = pk[0]; v.y = pk[1]; v.z = pk[2]; v.w = pk[3];
            *(uint4*)(xhatT + (size_t)c*MM + kb0 + h*32 + seg*8) = v;
        }
    }
}

// ---------------- query prep: q2 (sorted rows) = (l2norm(f)@G + kb2)*log2e, a = f@W1 ---
__global__ __launch_bounds__(256) void query_prep_kernel(
    const float* __restrict__ feat, const float* __restrict__ G,
    const float* __restrict__ kb2, const float* __restrict__ msgw,
    const int* __restrict__ qrank,
    unsigned short* __restrict__ q2, float* __restrict__ a)
{
    __shared__ float fl[4][128];
    const int t = threadIdx.x;
    const int w = t >> 6;
    const int lane = t & 63;
    const int b = blockIdx.x*4 + w;
    const int j0 = lane, j1 = lane + 64;
    float f0 = feat[b*CC + j0], f1 = feat[b*CC + j1];
    fl[w][j0] = f0; fl[w][j1] = f1;
    float s = f0*f0 + f1*f1;
    #pragma unroll
    for (int m2 = 1; m2 < 64; m2 <<= 1) s += __shfl_xor(s, m2, 64);
    float invn = 1.0f / fmaxf(sqrtf(s), 1e-12f);
    __syncthreads();
    float g0 = 0.f, g1 = 0.f, a0 = 0.f, a1 = 0.f;
    for (int i = 0; i < 128; ++i) {
        float x = fl[w][i];
        g0 = fmaf(x, G[i*128 + j0], g0);
        g1 = fmaf(x, G[i*128 + j1], g1);
        a0 = fmaf(x, msgw[i*128 + j0], a0);
        a1 = fmaf(x, msgw[i*128 + j1], a1);
    }
    const float LOG2E = 1.4426950408889634f;
    int rb = qrank[b];
    q2[rb*CC + j0] = f2bf((g0*invn + kb2[j0]) * LOG2E);
    q2[rb*CC + j1] = f2bf((g1*invn + kb2[j1]) * LOG2E);
    a[b*CC + j0] = a0;
    a[b*CC + j1] = a1;
}

// ---------------- flash attention with masked-tail tile skipping ----------------------
__global__ __launch_bounds__(256, 2) void attn_kernel(
    const unsigned short* __restrict__ xhat,
    const unsigned short* __restrict__ xhatT,
    const unsigned short* __restrict__ q2,
    const float* __restrict__ seed_s,
    const float* __restrict__ mst_s,
    const float* __restrict__ y_s,
    const float* __restrict__ tilemin,
    unsigned short* __restrict__ Upart,
    float* __restrict__ lpart,
    float* __restrict__ wypart)
{
    __shared__ __align__(16) unsigned short K_lds[64*128];   // swizzled, 16 KB
    __shared__ __align__(16) unsigned short VT_lds[128*64];  // swizzled, 16 KB
    __shared__ __align__(16) unsigned short P_lds[4][16*72]; // per-wave P, stride 72
    __shared__ float mst_lds[64];
    __shared__ float yf_lds[64];
    __shared__ int ntiles_s;

    const int tid = threadIdx.x;
    const int w = tid >> 6;
    const int lane = tid & 63;
    const int g = lane >> 4;
    const int l15 = lane & 15;
    const int qb = blockIdx.x;       // 0..31
    const int chunk = blockIdx.y;    // 0..31
    const int qrow0 = qb*64 + w*16;

    const float maxseed = seed_s[qb*64 + 63];   // queries sorted ascending
    if (tid < 64) {
        float tm = (tid < KCHUNK/64) ? tilemin[chunk*(KCHUNK/64) + tid] : 3.0e38f;
        unsigned long long act = __ballot(tm <= maxseed);
        if (tid == 0) ntiles_s = 64 - __clzll(act);
    }
    __syncthreads();
    const int ntiles = ntiles_s;   // 0 => zero-trip loop, epilogue writes zeros

    short8 qf[4];
    #pragma unroll
    for (int cs = 0; cs < 4; ++cs)
        qf[cs] = *(const short8*)(q2 + (qrow0 + l15)*CC + cs*32 + g*8);

    float seed_r[4];
    #pragma unroll
    for (int r = 0; r < 4; ++r) seed_r[r] = seed_s[qrow0 + g*4 + r];

    f32x4 accU[8];
    #pragma unroll
    for (int n = 0; n < 8; ++n) accU[n] = (f32x4)0.f;
    float accl[4] = {0.f, 0.f, 0.f, 0.f};
    float accw[4] = {0.f, 0.f, 0.f, 0.f};

    for (int kt2 = 0; kt2 < ntiles; ++kt2) {
        const int kb0 = chunk*KCHUNK + kt2*64;
        __syncthreads();
        #pragma unroll
        for (int i = 0; i < 4; ++i) {
            int cid = tid + i*256;
            int row = cid >> 4, cc = cid & 15;
            uint4 v = *(const uint4*)(xhat + (size_t)(kb0 + row)*CC + cc*8);
            *(uint4*)((char*)K_lds + row*256 + ((cc*16) ^ ((row & 7) << 4))) = v;
        }
        #pragma unroll
        for (int i = 0; i < 4; ++i) {
            int cid = tid + i*256;
            int c = cid >> 3, cc = cid & 7;
            uint4 v = *(const uint4*)(xhatT + (size_t)c*MM + kb0 + cc*8);
            *(uint4*)((char*)VT_lds + c*128 + ((cc*16) ^ ((c & 7) << 4))) = v;
        }
        if (tid < 64) {
            mst_lds[tid] = mst_s[kb0 + tid];
            yf_lds[tid] = y_s[kb0 + tid];
        }
        __syncthreads();

        #pragma unroll
        for (int sub = 0; sub < 4; ++sub) {
            f32x4 s = (f32x4)0.f;
            const int key = sub*16 + l15;
            #pragma unroll
            for (int cs = 0; cs < 4; ++cs) {
                short8 kf = *(const short8*)((const char*)K_lds + key*256 +
                                             ((cs*64 + g*16) ^ ((key & 7) << 4)));
                s = __builtin_amdgcn_mfma_f32_16x16x32_bf16(qf[cs], kf, s, 0, 0, 0);
            }
            float mstv = mst_lds[key];
            float yv = yf_lds[key];
            #pragma unroll
            for (int r = 0; r < 4; ++r) {
                float p = (seed_r[r] < mstv) ? 0.f : exp2f(s[r]);
                accl[r] += p;
                accw[r] += p * yv;
                P_lds[w][(g*4 + r)*72 + key] = f2bf(p);
            }
        }
        asm volatile("s_waitcnt lgkmcnt(0)" ::: "memory");
        #pragma unroll
        for (int kk = 0; kk < 2; ++kk) {
            short8 pa = *(const short8*)((const char*)&P_lds[w][0] + l15*144 + kk*64 + g*16);
            #pragma unroll
            for (int n = 0; n < 8; ++n) {
                const int c = n*16 + l15;
                short8 vf = *(const short8*)((const char*)VT_lds + c*128 +
                                             ((kk*64 + g*16) ^ ((c & 7) << 4)));
                accU[n] = __builtin_amdgcn_mfma_f32_16x16x32_bf16(pa, vf, accU[n], 0, 0, 0);
            }
        }
    }

    const int rbase = (qb*NSPLIT + chunk)*64 + w*16;
    #pragma unroll
    for (int r = 0; r < 4; ++r) {
        float lv = accl[r], wv = accw[r];
        #pragma unroll
        for (int m2 = 1; m2 < 16; m2 <<= 1) {
            lv += __shfl_xor(lv, m2, 64);
            wv += __shfl_xor(wv, m2, 64);
        }
        if (l15 == 0) {
            lpart[rbase + g*4 + r] = lv;
            wypart[rbase + g*4 + r] = wv;
        }
    }
    #pragma unroll
    for (int n = 0; n < 8; ++n) {
        #pragma unroll
        for (int r = 0; r < 4; ++r)
            Upart[(size_t)(rbase + g*4 + r)*CC + n*16 + l15] = f2bf(accU[n][r]);
    }
}

// ---------------- combine split-M partials --------------------------------------------
__global__ __launch_bounds__(256) void combine_l_kernel(
    const float* __restrict__ lpart, const float* __restrict__ wypart,
    float* __restrict__ ls, float* __restrict__ s1)
{
    int b = blockIdx.x*256 + threadIdx.x;
    int qb = b >> 6, r = b & 63;
    float l = 0.f, wy = 0.f;
    for (int s2 = 0; s2 < NSPLIT; ++s2) {
        int o = (qb*NSPLIT + s2)*64 + r;
        l += lpart[o];
        wy += wypart[o];
    }
    ls[b] = l;
    s1[b] = wy / l;
}

__global__ __launch_bounds__(256) void combine_U_kernel(
    const unsigned short* __restrict__ Upart, float* __restrict__ hpre)
{
    int idx = blockIdx.x*256 + threadIdx.x;  // 0..B*C/8-1
    int b = idx >> 4;
    int c8 = (idx & 15) * 8;
    int qb = b >> 6, r = b & 63;
    float acc[8] = {0.f,0.f,0.f,0.f,0.f,0.f,0.f,0.f};
    for (int s2 = 0; s2 < NSPLIT; ++s2) {
        short8 v = *(const short8*)(Upart + (size_t)((qb*NSPLIT + s2)*64 + r)*CC + c8);
        #pragma unroll
        for (int j = 0; j < 8; ++j) acc[j] += bf2f((unsigned short)v[j]);
    }
    float4 o0 = {acc[0], acc[1], acc[2], acc[3]};
    float4 o1 = {acc[4], acc[5], acc[6], acc[7]};
    *(float4*)(hpre + (size_t)b*CC + c8) = o0;
    *(float4*)(hpre + (size_t)b*CC + c8 + 4) = o1;
}

// ---------------- fused epilogue MLP (sorted rows -> original rows) --------------------
__global__ __launch_bounds__(256) void final_kernel(
    const float* __restrict__ feat, const float* __restrict__ hpre,
    const float* __restrict__ ls, const float* __restrict__ s1v,
    const float* __restrict__ a, const float* __restrict__ etab,
    const float* __restrict__ msgw, const int* __restrict__ qperm,
    const float* __restrict__ uw1, const float* __restrict__ ub1,
    const float* __restrict__ uw2, const float* __restrict__ ub2,
    float* __restrict__ out)
{
    __shared__ float fl[4][128], t0[4][128], t1l[4][128];
    const int t = threadIdx.x;
    const int w = t >> 6;
    const int lane = t & 63;
    const int b = blockIdx.x*4 + w;      // sorted row
    const int ob = qperm[b];             // original row
    const int j0 = lane, j1 = lane + 64;
    float f0 = feat[ob*CC + j0], f1 = feat[ob*CC + j1];
    fl[w][j0] = f0; fl[w][j1] = f1;
    t0[w][j0] = hpre[b*CC + j0];
    t0[w][j1] = hpre[b*CC + j1];
    __syncthreads();
    float linv = 1.0f / ls[b];
    float s1 = s1v[b];
    float acc0 = 0.f, acc1 = 0.f;
    for (int i = 0; i < 128; ++i) {
        float x = t0[w][i];
        acc0 = fmaf(x, msgw[(128 + i)*128 + j0], acc0);
        acc1 = fmaf(x, msgw[(128 + i)*128 + j1], acc1);
    }
    float mix0 = (1.f - s1)*etab[j0] + s1*etab[128 + j0];
    float mix1 = (1.f - s1)*etab[j1] + s1*etab[128 + j1];
    float hg0 = a[ob*CC + j0] + acc0*linv + mix0;
    float hg1 = a[ob*CC + j1] + acc1*linv + mix1;
    __syncthreads();
    t0[w][j0] = hg0; t0[w][j1] = hg1;
    __syncthreads();
    float h0 = ub1[j0], h1 = ub1[j1];
    for (int i = 0; i < 128; ++i) {
        float xf = fl[w][i];
        float xh = t0[w][i];
        h0 = fmaf(xf, uw1[i*128 + j0], h0);
        h1 = fmaf(xf, uw1[i*128 + j1], h1);
        h0 = fmaf(xh, uw1[(128 + i)*128 + j0], h0);
        h1 = fmaf(xh, uw1[(128 + i)*128 + j1], h1);
    }
    h0 = fmaxf(h0, 0.f); h1 = fmaxf(h1, 0.f);
    t1l[w][j0] = h0; t1l[w][j1] = h1;
    __syncthreads();
    float o0 = ub2[j0], o1 = ub2[j1];
    for (int i = 0; i < 128; ++i) {
        float x = t1l[w][i];
        o0 = fmaf(x, uw2[i*128 + j0], o0);
        o1 = fmaf(x, uw2[i*128 + j1], o1);
    }
    out[ob*CC + j0] = f0 + o0;
    out[ob*CC + j1] = f1 + o1;
}

extern "C" void kernel_launch(void* const* d_in, const int* in_sizes, int n_in,
                              void* d_out, int out_size, void* d_ws, size_t ws_size,
                              hipStream_t stream) {
    (void)in_sizes; (void)n_in; (void)out_size; (void)ws_size;
    const float* feature  = (const float*)d_in[0];
    const float* memory_x = (const float*)d_in[1];
    const int*   memory_y = (const int*)d_in[2];
    const float* seed_t   = (const float*)d_in[3];
    const float* mem_st   = (const float*)d_in[4];
    const float* key_w    = (const float*)d_in[5];
    const float* key_b    = (const float*)d_in[6];
    const float* msg_w    = (const float*)d_in[7];
    const float* msg_b    = (const float*)d_in[8];
    const float* upd_w1   = (const float*)d_in[9];
    const float* upd_b1   = (const float*)d_in[10];
    const float* upd_w2   = (const float*)d_in[11];
    const float* upd_b2   = (const float*)d_in[12];
    const float* y_emb    = (const float*)d_in[13];
    float* out = (float*)d_out;

    // ---- bump-allocated workspace layout (256 B aligned, no overlaps) ----
    char* ws = (char*)d_ws;
    size_t off = 0;
    auto A = [&](size_t bytes) -> char* {
        char* p = ws + off;
        off += (bytes + 255) & ~(size_t)255;
        return p;
    };
    unsigned short* xhat  = (unsigned short*)A((size_t)MM*CC*2);        // 16 MB
    unsigned short* xhatT = (unsigned short*)A((size_t)MM*CC*2);        // 16 MB
    unsigned short* q2    = (unsigned short*)A((size_t)BQ*CC*2);        // 512 KB
    float* a      = (float*)A((size_t)BQ*CC*4);                         // 1 MB
    float* G      = (float*)A((size_t)CC*CC*4);                         // 64 KB
    float* kb2    = (float*)A(CC*4);
    float* etab   = (float*)A(2*CC*4);
    float* lsv    = (float*)A(BQ*4);
    float* s1v    = (float*)A(BQ*4);
    float* hpre   = (float*)A((size_t)BQ*CC*4);                         // 1 MB
    float* lpart  = (float*)A((size_t)NQB*NSPLIT*64*4);                 // 256 KB
    float* wypart = (float*)A((size_t)NQB*NSPLIT*64*4);                 // 256 KB
    int*   dperm  = (int*)A((size_t)MM*4);                              // 256 KB
    float* mst_s  = (float*)A((size_t)MM*4);                            // 256 KB
    float* y_s    = (float*)A((size_t)MM*4);                            // 256 KB
    float* tmin   = (float*)A(NTILES*4);
    int*   qperm  = (int*)A(BQ*4);
    int*   qrank  = (int*)A(BQ*4);
    float* seed_s = (float*)A(BQ*4);
    unsigned short* Upart = (unsigned short*)A((size_t)BQ*NSPLIT*CC*2); // 16 MB
    // hist/gbase alias Upart: hist is consumed by sort_scatter_kernel, which
    // completes (stream order) before attn_kernel writes Upart.
    unsigned int* hist  = (unsigned int*)Upart;                         // 1 MB
    unsigned int* gbase = (unsigned int*)((char*)Upart + (size_t)(MM/256)*NBUCKET*4);

    prep_const_kernel<<<130, 128, 0, stream>>>(key_w, key_b, msg_w, msg_b, y_emb, G, kb2, etab);
    qrank_kernel<<<BQ/256, 256, 0, stream>>>(seed_t, qperm, qrank, seed_s);
    sort_hist_kernel<<<MM/256, 256, 0, stream>>>(mem_st, hist);
    sort_scan_kernel<<<1, 1024, 0, stream>>>(hist, gbase);
    sort_scatter_kernel<<<MM/256, 256, 0, stream>>>(mem_st, hist, gbase, dperm, mst_s);
    tilemin_kernel<<<1, 1024, 0, stream>>>(mst_s, tmin);
    mem_norm_kernel<<<MM/64, 256, 0, stream>>>(memory_x, dperm, memory_y, xhat, xhatT, y_s);
    query_prep_kernel<<<BQ/4, 256, 0, stream>>>(feature, G, kb2, msg_w, qrank, q2, a);
    attn_kernel<<<dim3(NQB, NSPLIT), 256, 0, stream>>>(xhat, xhatT, q2, seed_s, mst_s,
                                                       y_s, tmin, Upart, lpart, wypart);
    combine_l_kernel<<<BQ/256, 256, 0, stream>>>(lpart, wypart, lsv, s1v);
    combine_U_kernel<<<(BQ*CC/8)/256, 256, 0, stream>>>(Upart, hpre);
    final_kernel<<<BQ/4, 256, 0, stream>>>(feature, hpre, lsv, s1v, a, etab, msg_w, qperm,
                                           upd_w1, upd_b1, upd_w2, upd_b2, out);
}

// Round 4
// 254.861 us; speedup vs baseline: 1.2087x; 1.2087x over previous
//
#include <hip/hip_runtime.h>

#define BQ 2048
#define MM 65536
#define CC 128
#define NSPLIT 32
#define KCHUNK (MM/NSPLIT)
#define NQB (BQ/64)
#define NBUCKET 1024
#define NTILES (MM/64)
#define NTRI ((NQB*(NQB+1))/2)   // 528 lower-triangle cells

typedef short short8 __attribute__((ext_vector_type(8)));
typedef float f32x4 __attribute__((ext_vector_type(4)));

__device__ __forceinline__ unsigned short f2bf(float x) {
    unsigned int u = __builtin_bit_cast(unsigned int, x);
    u = (u + 0x7FFFu + ((u >> 16) & 1u)) >> 16;
    return (unsigned short)u;
}
__device__ __forceinline__ float bf2f(unsigned short u) {
    return __builtin_bit_cast(float, (unsigned int)u << 16);
}
__device__ __forceinline__ int bucket_of(float v) {
    return (int)fminf(fmaxf(v * 1024.0f, 0.0f), 1023.0f);
}

// ---------------- const prep: G = Kw@Kw^T, kb2 = key_b@Kw^T, etab = y_emb@W3 + msg_b ----
__global__ __launch_bounds__(128) void prep_const_kernel(
    const float* __restrict__ keyw, const float* __restrict__ keyb,
    const float* __restrict__ msgw, const float* __restrict__ msgb,
    const float* __restrict__ yemb,
    float* __restrict__ G, float* __restrict__ kb2, float* __restrict__ etab)
{
    __shared__ float rowd[128];
    int t = threadIdx.x;
    int d = blockIdx.x;
    if (d < 128) {
        rowd[t] = keyw[d*128 + t];
        __syncthreads();
        float acc = 0.f;
        for (int c2 = 0; c2 < 128; ++c2) acc = fmaf(rowd[c2], keyw[t*128 + c2], acc);
        G[d*128 + t] = acc;
    } else if (d == 128) {
        rowd[t] = keyb[t];
        __syncthreads();
        float acc = 0.f;
        for (int c2 = 0; c2 < 128; ++c2) acc = fmaf(rowd[c2], keyw[t*128 + c2], acc);
        kb2[t] = acc;
    } else {
        float acc0 = msgb[t], acc1 = msgb[t];
        for (int c2 = 0; c2 < 128; ++c2) {
            float w3 = msgw[(256 + c2)*128 + t];
            acc0 = fmaf(yemb[c2], w3, acc0);
            acc1 = fmaf(yemb[128 + c2], w3, acc1);
        }
        etab[t] = acc0;
        etab[128 + t] = acc1;
    }
}

// ---------------- deterministic counting sort of memory keys by mst -------------------
// histT layout: [bucket][block]  (transposed for parallel scan)
__global__ __launch_bounds__(256) void sort_hist_kernel(
    const float* __restrict__ mst, unsigned int* __restrict__ histT)
{
    __shared__ unsigned int h[NBUCKET];
    int t = threadIdx.x, b = blockIdx.x;
    #pragma unroll
    for (int j = t; j < NBUCKET; j += 256) h[j] = 0;
    __syncthreads();
    int bin = bucket_of(mst[b*256 + t]);
    atomicAdd(&h[bin], 1u);
    __syncthreads();
    #pragma unroll
    for (int j = t; j < NBUCKET; j += 256) histT[(size_t)j*256 + b] = h[j];
}

// scanA: per bucket, exclusive prefix over the 256 block-counts (1 wave per bucket)
__global__ __launch_bounds__(64) void sort_scanA_kernel(
    unsigned int* __restrict__ histT, unsigned int* __restrict__ btot)
{
    int j = blockIdx.x;      // bucket
    int t = threadIdx.x;     // 0..63
    uint4 v = *(uint4*)(histT + (size_t)j*256 + t*4);
    unsigned int s0 = v.x, s1 = v.y, s2 = v.z, s3 = v.w;
    unsigned int tsum = s0 + s1 + s2 + s3;
    unsigned int inc = tsum;
    #pragma unroll
    for (int off = 1; off < 64; off <<= 1) {
        unsigned int n = __shfl_up(inc, off, 64);
        if (t >= off) inc += n;
    }
    unsigned int ex = inc - tsum;
    uint4 o;
    o.x = ex; o.y = ex + s0; o.z = ex + s0 + s1; o.w = ex + s0 + s1 + s2;
    *(uint4*)(histT + (size_t)j*256 + t*4) = o;
    if (t == 63) btot[j] = inc;
}

// scanB: exclusive prefix over bucket totals -> gbase
__global__ __launch_bounds__(1024) void sort_scanB_kernel(
    const unsigned int* __restrict__ btot, unsigned int* __restrict__ gbase)
{
    __shared__ unsigned int sc[NBUCKET];
    int j = threadIdx.x;
    unsigned int tot = btot[j];
    sc[j] = tot;
    __syncthreads();
    for (int off = 1; off < NBUCKET; off <<= 1) {
        unsigned int y = (j >= off) ? sc[j - off] : 0u;
        __syncthreads();
        sc[j] += y;
        __syncthreads();
    }
    gbase[j] = sc[j] - tot;
}

__global__ __launch_bounds__(256) void sort_scatter_kernel(
    const float* __restrict__ mst, const unsigned int* __restrict__ histT,
    const unsigned int* __restrict__ gbase,
    int* __restrict__ dperm, float* __restrict__ mst_s)
{
    __shared__ int bins[256];
    int t = threadIdx.x, b = blockIdx.x;
    int i = b*256 + t;
    float v = mst[i];
    int bin = bucket_of(v);
    bins[t] = bin;
    __syncthreads();
    int pos = 0;
    for (int j = 0; j < t; ++j) pos += (bins[j] == bin);
    unsigned int dest = gbase[bin] + histT[(size_t)bin*256 + b] + pos;
    dperm[dest] = i;
    mst_s[dest] = v;
}

// ---------------- exact query rank by seed_time (deterministic) -----------------------
__global__ __launch_bounds__(256) void qrank_kernel(
    const float* __restrict__ seed, int* __restrict__ qperm,
    int* __restrict__ qrank, float* __restrict__ seed_s)
{
    __shared__ float sl[256];
    int q = blockIdx.x*256 + threadIdx.x;
    float v = seed[q];
    int r = 0;
    for (int t0 = 0; t0 < BQ; t0 += 256) {
        sl[threadIdx.x] = seed[t0 + threadIdx.x];
        __syncthreads();
        for (int j = 0; j < 256; ++j) {
            float u = sl[j];
            int gj = t0 + j;
            r += (u < v) || (u == v && gj < q);
        }
        __syncthreads();
    }
    qperm[r] = q;
    qrank[q] = r;
    seed_s[r] = v;
}

// ---------------- plan: active-chunk prefix length per q-block ------------------------
// chunk active iff bucket_floor(mst_s[chunk*KCHUNK]) <= maxseed(qb). lb nondecreasing
// in chunk => active set is a prefix. Identical formula used implicitly by attn's
// tile test, so attn writes exactly the cells combine reads.
__global__ __launch_bounds__(64) void plan_kernel(
    const float* __restrict__ seed_s, const float* __restrict__ mst_s,
    int* __restrict__ nactq)
{
    int qb = threadIdx.x;
    if (qb >= NQB) return;
    float maxseed = seed_s[qb*64 + 63];
    int n = 0;
    for (int c = 0; c < NSPLIT; ++c) {
        float lb = (float)bucket_of(mst_s[(size_t)c*KCHUNK]) * (1.0f/1024.0f);
        n += (lb <= maxseed) ? 1 : 0;
    }
    nactq[qb] = n < 1 ? 1 : n;
}

// ---------------- memory l2norm (gathered via dperm) -> xhat + xhatT + y_s -------------
__global__ __launch_bounds__(256) void mem_norm_kernel(
    const float* __restrict__ mx, const int* __restrict__ dperm,
    const int* __restrict__ memy,
    unsigned short* __restrict__ xhat, unsigned short* __restrict__ xhatT,
    float* __restrict__ y_s)
{
    __shared__ __align__(16) float tile[64*132];
    __shared__ float rs[64];
    __shared__ float invn[64];
    __shared__ int operm[64];
    const int t = threadIdx.x;
    const int lane = t & 63;
    const int kb0 = blockIdx.x * 64;

    if (t < 64) operm[t] = dperm[kb0 + t];
    __syncthreads();
    if (t < 64) y_s[kb0 + t] = (float)memy[operm[t]];

    float4 vals[8];
    int rows[8];
    #pragma unroll
    for (int i = 0; i < 8; ++i) {
        int idx = t + 256*i;            // float4 id 0..2047
        int e = idx * 4;
        int row = e >> 7, col = e & 127;
        float4 v = *(const float4*)(mx + (size_t)operm[row]*CC + col);
        vals[i] = v; rows[i] = row;
        *(float4*)&tile[row*132 + col] = v;
        float s = v.x*v.x + v.y*v.y + v.z*v.z + v.w*v.w;
        #pragma unroll
        for (int m2 = 1; m2 < 32; m2 <<= 1) s += __shfl_xor(s, m2, 64);
        if ((lane & 31) == 0) rs[row] = s;
    }
    __syncthreads();
    if (t < 64) invn[t] = 1.0f / fmaxf(sqrtf(rs[t]), 1e-12f);
    __syncthreads();
    #pragma unroll
    for (int i = 0; i < 8; ++i) {
        float sc = invn[rows[i]];
        float4 v = vals[i];
        ushort4 o;
        o.x = f2bf(v.x*sc); o.y = f2bf(v.y*sc); o.z = f2bf(v.z*sc); o.w = f2bf(v.w*sc);
        int idx = t + 256*i;
        *(ushort4*)(xhat + (size_t)kb0*CC + idx*4) = o;
    }
    {
        int c = t >> 1, h = t & 1;
        #pragma unroll
        for (int seg = 0; seg < 4; ++seg) {
            unsigned int pk[4];
            #pragma unroll
            for (int j = 0; j < 4; ++j) {
                int k0 = h*32 + seg*8 + j*2;
                unsigned int lo = f2bf(tile[k0*132 + c] * invn[k0]);
                unsigned int hi = f2bf(tile[(k0+1)*132 + c] * invn[k0+1]);
                pk[j] = lo | (hi << 16);
            }
            uint4 v; v.x = pk[0]; v.y = pk[1]; v.z = pk[2]; v.w = pk[3];
            *(uint4*)(xhatT + (size_t)c*MM + kb0 + h*32 + seg*8) = v;
        }
    }
}

// ---------------- query prep: q2 (sorted rows) = (l2norm(f)@G + kb2)*log2e, a = f@W1 ---
__global__ __launch_bounds__(256) void query_prep_kernel(
    const float* __restrict__ feat, const float* __restrict__ G,
    const float* __restrict__ kb2, const float* __restrict__ msgw,
    const int* __restrict__ qrank,
    unsigned short* __restrict__ q2, float* __restrict__ a)
{
    __shared__ float fl[4][128];
    const int t = threadIdx.x;
    const int w = t >> 6;
    const int lane = t & 63;
    const int b = blockIdx.x*4 + w;
    const int j0 = lane, j1 = lane + 64;
    float f0 = feat[b*CC + j0], f1 = feat[b*CC + j1];
    fl[w][j0] = f0; fl[w][j1] = f1;
    float s = f0*f0 + f1*f1;
    #pragma unroll
    for (int m2 = 1; m2 < 64; m2 <<= 1) s += __shfl_xor(s, m2, 64);
    float invn = 1.0f / fmaxf(sqrtf(s), 1e-12f);
    __syncthreads();
    float g0 = 0.f, g1 = 0.f, a0 = 0.f, a1 = 0.f;
    for (int i = 0; i < 128; ++i) {
        float x = fl[w][i];
        g0 = fmaf(x, G[i*128 + j0], g0);
        g1 = fmaf(x, G[i*128 + j1], g1);
        a0 = fmaf(x, msgw[i*128 + j0], a0);
        a1 = fmaf(x, msgw[i*128 + j1], a1);
    }
    const float LOG2E = 1.4426950408889634f;
    int rb = qrank[b];
    q2[rb*CC + j0] = f2bf((g0*invn + kb2[j0]) * LOG2E);
    q2[rb*CC + j1] = f2bf((g1*invn + kb2[j1]) * LOG2E);
    a[b*CC + j0] = a0;
    a[b*CC + j1] = a1;
}

// ---------------- flash attention: triangle-ordered 1D grid ---------------------------
// id < 528: (qb,chunk) with chunk<=qb (the ~equal-work heavy cells), scheduled first.
// id >= 528: chunk>qb cells — nearly all inactive, exit immediately, scheduled last.
__global__ __launch_bounds__(256, 2) void attn_kernel(
    const unsigned short* __restrict__ xhat,
    const unsigned short* __restrict__ xhatT,
    const unsigned short* __restrict__ q2,
    const float* __restrict__ seed_s,
    const float* __restrict__ mst_s,
    const float* __restrict__ y_s,
    const int* __restrict__ nactq,
    unsigned short* __restrict__ Upart,
    float* __restrict__ lpart,
    float* __restrict__ wypart)
{
    __shared__ __align__(16) unsigned short K_lds[64*128];   // swizzled, 16 KB
    __shared__ __align__(16) unsigned short VT_lds[128*64];  // swizzled, 16 KB
    __shared__ __align__(16) unsigned short P_lds[4][16*72]; // per-wave P, stride 72
    __shared__ float mst_lds[64];
    __shared__ float yf_lds[64];
    __shared__ int ntiles_s;

    const int tid = threadIdx.x;
    const int w = tid >> 6;
    const int lane = tid & 63;
    const int g = lane >> 4;
    const int l15 = lane & 15;

    // triangle id -> (qb, chunk)
    int qb, chunk;
    {
        int id = blockIdx.x;
        if (id < NTRI) {
            int q = 0, base = 0;
            while (id >= base + q + 1) { base += q + 1; ++q; }
            qb = q; chunk = id - base;
        } else {
            int k = id - NTRI;          // strict upper triangle, row qb has 31-qb cells
            int q = 0;
            while (k >= (NQB - 1) - q) { k -= (NQB - 1) - q; ++q; }
            qb = q; chunk = q + 1 + k;
        }
    }
    if (chunk >= nactq[qb]) return;      // inactive cell: no writes, combine skips it

    const int qrow0 = qb*64 + w*16;
    const float maxseed = seed_s[qb*64 + 63];   // queries sorted ascending

    if (tid < 64) {
        float tm = 3.0e38f;
        if (tid < KCHUNK/64)
            tm = (float)bucket_of(mst_s[(size_t)(chunk*(KCHUNK/64) + tid)*64]) * (1.0f/1024.0f);
        unsigned long long act = __ballot(tm <= maxseed);
        if (tid == 0) ntiles_s = 64 - __clzll(act);
    }
    __syncthreads();
    const int ntiles = ntiles_s;   // >=1 for active cells

    short8 qf[4];
    #pragma unroll
    for (int cs = 0; cs < 4; ++cs)
        qf[cs] = *(const short8*)(q2 + (qrow0 + l15)*CC + cs*32 + g*8);

    float seed_r[4];
    #pragma unroll
    for (int r = 0; r < 4; ++r) seed_r[r] = seed_s[qrow0 + g*4 + r];

    f32x4 accU[8];
    #pragma unroll
    for (int n = 0; n < 8; ++n) accU[n] = (f32x4)0.f;
    float accl[4] = {0.f, 0.f, 0.f, 0.f};
    float accw[4] = {0.f, 0.f, 0.f, 0.f};

    for (int kt2 = 0; kt2 < ntiles; ++kt2) {
        const int kb0 = chunk*KCHUNK + kt2*64;
        __syncthreads();
        #pragma unroll
        for (int i = 0; i < 4; ++i) {
            int cid = tid + i*256;
            int row = cid >> 4, cc = cid & 15;
            uint4 v = *(const uint4*)(xhat + (size_t)(kb0 + row)*CC + cc*8);
            *(uint4*)((char*)K_lds + row*256 + ((cc*16) ^ ((row & 7) << 4))) = v;
        }
        #pragma unroll
        for (int i = 0; i < 4; ++i) {
            int cid = tid + i*256;
            int c = cid >> 3, cc = cid & 7;
            uint4 v = *(const uint4*)(xhatT + (size_t)c*MM + kb0 + cc*8);
            *(uint4*)((char*)VT_lds + c*128 + ((cc*16) ^ ((c & 7) << 4))) = v;
        }
        if (tid < 64) {
            mst_lds[tid] = mst_s[kb0 + tid];
            yf_lds[tid] = y_s[kb0 + tid];
        }
        __syncthreads();

        #pragma unroll
        for (int sub = 0; sub < 4; ++sub) {
            f32x4 s = (f32x4)0.f;
            const int key = sub*16 + l15;
            #pragma unroll
            for (int cs = 0; cs < 4; ++cs) {
                short8 kf = *(const short8*)((const char*)K_lds + key*256 +
                                             ((cs*64 + g*16) ^ ((key & 7) << 4)));
                s = __builtin_amdgcn_mfma_f32_16x16x32_bf16(qf[cs], kf, s, 0, 0, 0);
            }
            float mstv = mst_lds[key];
            float yv = yf_lds[key];
            #pragma unroll
            for (int r = 0; r < 4; ++r) {
                float p = (seed_r[r] < mstv) ? 0.f : exp2f(s[r]);
                accl[r] += p;
                accw[r] += p * yv;
                P_lds[w][(g*4 + r)*72 + key] = f2bf(p);
            }
        }
        asm volatile("s_waitcnt lgkmcnt(0)" ::: "memory");
        #pragma unroll
        for (int kk = 0; kk < 2; ++kk) {
            short8 pa = *(const short8*)((const char*)&P_lds[w][0] + l15*144 + kk*64 + g*16);
            #pragma unroll
            for (int n = 0; n < 8; ++n) {
                const int c = n*16 + l15;
                short8 vf = *(const short8*)((const char*)VT_lds + c*128 +
                                             ((kk*64 + g*16) ^ ((c & 7) << 4)));
                accU[n] = __builtin_amdgcn_mfma_f32_16x16x32_bf16(pa, vf, accU[n], 0, 0, 0);
            }
        }
    }

    const int rbase = (qb*NSPLIT + chunk)*64 + w*16;
    #pragma unroll
    for (int r = 0; r < 4; ++r) {
        float lv = accl[r], wv = accw[r];
        #pragma unroll
        for (int m2 = 1; m2 < 16; m2 <<= 1) {
            lv += __shfl_xor(lv, m2, 64);
            wv += __shfl_xor(wv, m2, 64);
        }
        if (l15 == 0) {
            lpart[rbase + g*4 + r] = lv;
            wypart[rbase + g*4 + r] = wv;
        }
    }
    #pragma unroll
    for (int n = 0; n < 8; ++n) {
        #pragma unroll
        for (int r = 0; r < 4; ++r)
            Upart[(size_t)(rbase + g*4 + r)*CC + n*16 + l15] = f2bf(accU[n][r]);
    }
}

// ---------------- combine split-M partials (only active chunks) -----------------------
__global__ __launch_bounds__(256) void combine_l_kernel(
    const float* __restrict__ lpart, const float* __restrict__ wypart,
    const int* __restrict__ nactq,
    float* __restrict__ ls, float* __restrict__ s1)
{
    int b = blockIdx.x*256 + threadIdx.x;
    int qb = b >> 6, r = b & 63;
    int na = nactq[qb];
    float l = 0.f, wy = 0.f;
    for (int s2 = 0; s2 < na; ++s2) {
        int o = (qb*NSPLIT + s2)*64 + r;
        l += lpart[o];
        wy += wypart[o];
    }
    ls[b] = l;
    s1[b] = wy / l;
}

__global__ __launch_bounds__(256) void combine_U_kernel(
    const unsigned short* __restrict__ Upart, const int* __restrict__ nactq,
    float* __restrict__ hpre)
{
    int idx = blockIdx.x*256 + threadIdx.x;  // 0..B*C/8-1
    int b = idx >> 4;
    int c8 = (idx & 15) * 8;
    int qb = b >> 6, r = b & 63;
    int na = nactq[qb];
    float acc[8] = {0.f,0.f,0.f,0.f,0.f,0.f,0.f,0.f};
    for (int s2 = 0; s2 < na; ++s2) {
        short8 v = *(const short8*)(Upart + (size_t)((qb*NSPLIT + s2)*64 + r)*CC + c8);
        #pragma unroll
        for (int j = 0; j < 8; ++j) acc[j] += bf2f((unsigned short)v[j]);
    }
    float4 o0 = {acc[0], acc[1], acc[2], acc[3]};
    float4 o1 = {acc[4], acc[5], acc[6], acc[7]};
    *(float4*)(hpre + (size_t)b*CC + c8) = o0;
    *(float4*)(hpre + (size_t)b*CC + c8 + 4) = o1;
}

// ---------------- fused epilogue MLP (sorted rows -> original rows) --------------------
__global__ __launch_bounds__(256) void final_kernel(
    const float* __restrict__ feat, const float* __restrict__ hpre,
    const float* __restrict__ ls, const float* __restrict__ s1v,
    const float* __restrict__ a, const float* __restrict__ etab,
    const float* __restrict__ msgw, const int* __restrict__ qperm,
    const float* __restrict__ uw1, const float* __restrict__ ub1,
    const float* __restrict__ uw2, const float* __restrict__ ub2,
    float* __restrict__ out)
{
    __shared__ float fl[4][128], t0[4][128], t1l[4][128];
    const int t = threadIdx.x;
    const int w = t >> 6;
    const int lane = t & 63;
    const int b = blockIdx.x*4 + w;      // sorted row
    const int ob = qperm[b];             // original row
    const int j0 = lane, j1 = lane + 64;
    float f0 = feat[ob*CC + j0], f1 = feat[ob*CC + j1];
    fl[w][j0] = f0; fl[w][j1] = f1;
    t0[w][j0] = hpre[b*CC + j0];
    t0[w][j1] = hpre[b*CC + j1];
    __syncthreads();
    float linv = 1.0f / ls[b];
    float s1 = s1v[b];
    float acc0 = 0.f, acc1 = 0.f;
    for (int i = 0; i < 128; ++i) {
        float x = t0[w][i];
        acc0 = fmaf(x, msgw[(128 + i)*128 + j0], acc0);
        acc1 = fmaf(x, msgw[(128 + i)*128 + j1], acc1);
    }
    float mix0 = (1.f - s1)*etab[j0] + s1*etab[128 + j0];
    float mix1 = (1.f - s1)*etab[j1] + s1*etab[128 + j1];
    float hg0 = a[ob*CC + j0] + acc0*linv + mix0;
    float hg1 = a[ob*CC + j1] + acc1*linv + mix1;
    __syncthreads();
    t0[w][j0] = hg0; t0[w][j1] = hg1;
    __syncthreads();
    float h0 = ub1[j0], h1 = ub1[j1];
    for (int i = 0; i < 128; ++i) {
        float xf = fl[w][i];
        float xh = t0[w][i];
        h0 = fmaf(xf, uw1[i*128 + j0], h0);
        h1 = fmaf(xf, uw1[i*128 + j1], h1);
        h0 = fmaf(xh, uw1[(128 + i)*128 + j0], h0);
        h1 = fmaf(xh, uw1[(128 + i)*128 + j1], h1);
    }
    h0 = fmaxf(h0, 0.f); h1 = fmaxf(h1, 0.f);
    t1l[w][j0] = h0; t1l[w][j1] = h1;
    __syncthreads();
    float o0 = ub2[j0], o1 = ub2[j1];
    for (int i = 0; i < 128; ++i) {
        float x = t1l[w][i];
        o0 = fmaf(x, uw2[i*128 + j0], o0);
        o1 = fmaf(x, uw2[i*128 + j1], o1);
    }
    out[ob*CC + j0] = f0 + o0;
    out[ob*CC + j1] = f1 + o1;
}

extern "C" void kernel_launch(void* const* d_in, const int* in_sizes, int n_in,
                              void* d_out, int out_size, void* d_ws, size_t ws_size,
                              hipStream_t stream) {
    (void)in_sizes; (void)n_in; (void)out_size; (void)ws_size;
    const float* feature  = (const float*)d_in[0];
    const float* memory_x = (const float*)d_in[1];
    const int*   memory_y = (const int*)d_in[2];
    const float* seed_t   = (const float*)d_in[3];
    const float* mem_st   = (const float*)d_in[4];
    const float* key_w    = (const float*)d_in[5];
    const float* key_b    = (const float*)d_in[6];
    const float* msg_w    = (const float*)d_in[7];
    const float* msg_b    = (const float*)d_in[8];
    const float* upd_w1   = (const float*)d_in[9];
    const float* upd_b1   = (const float*)d_in[10];
    const float* upd_w2   = (const float*)d_in[11];
    const float* upd_b2   = (const float*)d_in[12];
    const float* y_emb    = (const float*)d_in[13];
    float* out = (float*)d_out;

    // ---- bump-allocated workspace layout (256 B aligned, no overlaps) ----
    char* ws = (char*)d_ws;
    size_t off = 0;
    auto A = [&](size_t bytes) -> char* {
        char* p = ws + off;
        off += (bytes + 255) & ~(size_t)255;
        return p;
    };
    unsigned short* xhat  = (unsigned short*)A((size_t)MM*CC*2);        // 16 MB
    unsigned short* xhatT = (unsigned short*)A((size_t)MM*CC*2);        // 16 MB
    unsigned short* q2    = (unsigned short*)A((size_t)BQ*CC*2);        // 512 KB
    float* a      = (float*)A((size_t)BQ*CC*4);                         // 1 MB
    float* G      = (float*)A((size_t)CC*CC*4);                         // 64 KB
    float* kb2    = (float*)A(CC*4);
    float* etab   = (float*)A(2*CC*4);
    float* lsv    = (float*)A(BQ*4);
    float* s1v    = (float*)A(BQ*4);
    float* hpre   = (float*)A((size_t)BQ*CC*4);                         // 1 MB
    float* lpart  = (float*)A((size_t)NQB*NSPLIT*64*4);                 // 256 KB
    float* wypart = (float*)A((size_t)NQB*NSPLIT*64*4);                 // 256 KB
    int*   dperm  = (int*)A((size_t)MM*4);                              // 256 KB
    float* mst_s  = (float*)A((size_t)MM*4);                            // 256 KB
    float* y_s    = (float*)A((size_t)MM*4);                            // 256 KB
    unsigned int* histT = (unsigned int*)A((size_t)NBUCKET*256*4);      // 1 MB
    unsigned int* btot  = (unsigned int*)A(NBUCKET*4);
    unsigned int* gbase = (unsigned int*)A(NBUCKET*4);
    int*   nactq  = (int*)A(NQB*4);
    int*   qperm  = (int*)A(BQ*4);
    int*   qrank  = (int*)A(BQ*4);
    float* seed_s = (float*)A(BQ*4);
    unsigned short* Upart = (unsigned short*)A((size_t)BQ*NSPLIT*CC*2); // 16 MB

    prep_const_kernel<<<130, 128, 0, stream>>>(key_w, key_b, msg_w, msg_b, y_emb, G, kb2, etab);
    qrank_kernel<<<BQ/256, 256, 0, stream>>>(seed_t, qperm, qrank, seed_s);
    sort_hist_kernel<<<MM/256, 256, 0, stream>>>(mem_st, histT);
    sort_scanA_kernel<<<NBUCKET, 64, 0, stream>>>(histT, btot);
    sort_scanB_kernel<<<1, 1024, 0, stream>>>(btot, gbase);
    sort_scatter_kernel<<<MM/256, 256, 0, stream>>>(mem_st, histT, gbase, dperm, mst_s);
    plan_kernel<<<1, 64, 0, stream>>>(seed_s, mst_s, nactq);
    mem_norm_kernel<<<MM/64, 256, 0, stream>>>(memory_x, dperm, memory_y, xhat, xhatT, y_s);
    query_prep_kernel<<<BQ/4, 256, 0, stream>>>(feature, G, kb2, msg_w, qrank, q2, a);
    attn_kernel<<<NQB*NSPLIT, 256, 0, stream>>>(xhat, xhatT, q2, seed_s, mst_s,
                                                y_s, nactq, Upart, lpart, wypart);
    combine_l_kernel<<<BQ/256, 256, 0, stream>>>(lpart, wypart, nactq, lsv, s1v);
    combine_U_kernel<<<(BQ*CC/8)/256, 256, 0, stream>>>(Upart, nactq, hpre);
    final_kernel<<<BQ/4, 256, 0, stream>>>(feature, hpre, lsv, s1v, a, etab, msg_w, qperm,
                                           upd_w1, upd_b1, upd_w2, upd_b2, out);
}

// Round 5
// 226.163 us; speedup vs baseline: 1.3621x; 1.1269x over previous
//
#include <hip/hip_runtime.h>

#define BQ 2048
#define MM 65536
#define CC 128
#define NSPLIT 32
#define KCHUNK (MM/NSPLIT)
#define NQB (BQ/64)
#define NBUCKET 1024
#define NTRI ((NQB*(NQB+1))/2)   // 528 lower-triangle cells

typedef short short8 __attribute__((ext_vector_type(8)));
typedef float f32x4 __attribute__((ext_vector_type(4)));

__device__ __forceinline__ unsigned short f2bf(float x) {
    unsigned int u = __builtin_bit_cast(unsigned int, x);
    u = (u + 0x7FFFu + ((u >> 16) & 1u)) >> 16;
    return (unsigned short)u;
}
__device__ __forceinline__ float bf2f(unsigned short u) {
    return __builtin_bit_cast(float, (unsigned int)u << 16);
}
__device__ __forceinline__ int bucket_of(float v) {
    return (int)fminf(fmaxf(v * 1024.0f, 0.0f), 1023.0f);
}

// ---------------- etab = y_emb@W3 + msg_b (tiny) --------------------------------------
__global__ __launch_bounds__(128) void etab_kernel(
    const float* __restrict__ msgw, const float* __restrict__ msgb,
    const float* __restrict__ yemb, float* __restrict__ etab)
{
    int t = threadIdx.x;
    float acc0 = msgb[t], acc1 = msgb[t];
    for (int c2 = 0; c2 < 128; ++c2) {
        float w3 = msgw[(256 + c2)*128 + t];
        acc0 = fmaf(yemb[c2], w3, acc0);
        acc1 = fmaf(yemb[128 + c2], w3, acc1);
    }
    etab[t] = acc0;
    etab[128 + t] = acc1;
}

// ---------------- exact query rank by seed_time (parallel, deterministic) -------------
__global__ __launch_bounds__(256) void qrank_kernel(
    const float* __restrict__ seed, int* __restrict__ qperm,
    int* __restrict__ qrank, float* __restrict__ seed_s)
{
    int t = threadIdx.x;
    int q = blockIdx.x*8 + (t >> 5);
    int l32 = t & 31;
    float v = seed[q];
    int r = 0;
    for (int seg = 0; seg < 64; ++seg) {
        int j = seg*32 + l32;
        float u = seed[j];
        r += (u < v) || (u == v && j < q);
    }
    #pragma unroll
    for (int m2 = 1; m2 < 32; m2 <<= 1) r += __shfl_xor(r, m2, 32);
    if (l32 == 0) { qperm[r] = q; qrank[q] = r; seed_s[r] = v; }
}

// ---------------- counting sort of memory keys by mst ---------------------------------
__global__ __launch_bounds__(256) void sort_hist_kernel(
    const float* __restrict__ mst, unsigned int* __restrict__ histT)
{
    __shared__ unsigned int h[NBUCKET];
    int t = threadIdx.x, b = blockIdx.x;
    #pragma unroll
    for (int j = t; j < NBUCKET; j += 256) h[j] = 0;
    __syncthreads();
    int bin = bucket_of(mst[b*256 + t]);
    atomicAdd(&h[bin], 1u);
    __syncthreads();
    #pragma unroll
    for (int j = t; j < NBUCKET; j += 256) histT[(size_t)j*256 + b] = h[j];
}

__global__ __launch_bounds__(64) void sort_scanA_kernel(
    unsigned int* __restrict__ histT, unsigned int* __restrict__ btot)
{
    int j = blockIdx.x;
    int t = threadIdx.x;
    uint4 v = *(uint4*)(histT + (size_t)j*256 + t*4);
    unsigned int s0 = v.x, s1 = v.y, s2 = v.z, s3 = v.w;
    unsigned int tsum = s0 + s1 + s2 + s3;
    unsigned int inc = tsum;
    #pragma unroll
    for (int off = 1; off < 64; off <<= 1) {
        unsigned int n = __shfl_up(inc, off, 64);
        if (t >= off) inc += n;
    }
    unsigned int ex = inc - tsum;
    uint4 o;
    o.x = ex; o.y = ex + s0; o.z = ex + s0 + s1; o.w = ex + s0 + s1 + s2;
    *(uint4*)(histT + (size_t)j*256 + t*4) = o;
    if (t == 63) btot[j] = inc;
}

__global__ __launch_bounds__(1024) void sort_scanB_kernel(
    const unsigned int* __restrict__ btot, unsigned int* __restrict__ gbase)
{
    __shared__ unsigned int sc[NBUCKET];
    int j = threadIdx.x;
    unsigned int tot = btot[j];
    sc[j] = tot;
    __syncthreads();
    for (int off = 1; off < NBUCKET; off <<= 1) {
        unsigned int y = (j >= off) ? sc[j - off] : 0u;
        __syncthreads();
        sc[j] += y;
        __syncthreads();
    }
    gbase[j] = sc[j] - tot;
}

__global__ __launch_bounds__(256) void sort_scatter_kernel(
    const float* __restrict__ mst, const unsigned int* __restrict__ histT,
    const unsigned int* __restrict__ gbase,
    int* __restrict__ dperm, float* __restrict__ mst_s)
{
    __shared__ int bins[256];
    int t = threadIdx.x, b = blockIdx.x;
    int i = b*256 + t;
    float v = mst[i];
    int bin = bucket_of(v);
    bins[t] = bin;
    __syncthreads();
    int pos = 0;
    for (int j = 0; j < t; ++j) pos += (bins[j] == bin);
    unsigned int dest = gbase[bin] + histT[(size_t)bin*256 + b] + pos;
    dperm[dest] = i;
    mst_s[dest] = v;
}

// ---------------- memory l2norm (gathered) -> xhat + xhatT, both coalesced ------------
__global__ __launch_bounds__(256) void mem_norm_kernel(
    const float* __restrict__ mx, const int* __restrict__ dperm,
    const int* __restrict__ memy,
    unsigned short* __restrict__ xhat, unsigned short* __restrict__ xhatT,
    float* __restrict__ y_s)
{
    __shared__ __align__(16) unsigned short tile[128*132];  // bf16, stride 132
    __shared__ float rs[128];
    __shared__ float invn[128];
    __shared__ int operm[128];
    const int t = threadIdx.x;
    const int kb0 = blockIdx.x * 128;

    if (t < 128) operm[t] = dperm[kb0 + t];
    __syncthreads();
    if (t < 128) y_s[kb0 + t] = (float)memy[operm[t]];

    float4 vals[16];
    #pragma unroll
    for (int i = 0; i < 16; ++i) {
        int f4 = t + 256*i;              // 4096 float4s = 128 rows x 32
        int row = f4 >> 5, col4 = f4 & 31;
        float4 v = *(const float4*)(mx + (size_t)operm[row]*CC + col4*4);
        vals[i] = v;
        float s = v.x*v.x + v.y*v.y + v.z*v.z + v.w*v.w;
        #pragma unroll
        for (int m2 = 1; m2 < 32; m2 <<= 1) s += __shfl_xor(s, m2, 64);
        if ((t & 31) == 0) rs[row] = s;
    }
    __syncthreads();
    if (t < 128) invn[t] = 1.0f / fmaxf(sqrtf(rs[t]), 1e-12f);
    __syncthreads();
    #pragma unroll
    for (int i = 0; i < 16; ++i) {
        int f4 = t + 256*i;
        int row = f4 >> 5, col4 = f4 & 31;
        float sc = invn[row];
        float4 v = vals[i];
        ushort4 o;
        o.x = f2bf(v.x*sc); o.y = f2bf(v.y*sc); o.z = f2bf(v.z*sc); o.w = f2bf(v.w*sc);
        *(ushort4*)&tile[row*132 + col4*4] = o;   // 132 % 4 == 0 -> 8B aligned
    }
    __syncthreads();
    // xhat row-major, coalesced
    #pragma unroll
    for (int i = 0; i < 8; ++i) {
        int u = t + 256*i;               // 2048 us8 units = 128 rows x 16
        int row = u >> 4, c8 = u & 15;
        ushort4 a0 = *(ushort4*)&tile[row*132 + c8*8];
        ushort4 a1 = *(ushort4*)&tile[row*132 + c8*8 + 4];
        *(ushort4*)(xhat + (size_t)(kb0 + row)*CC + c8*8) = a0;
        *(ushort4*)(xhat + (size_t)(kb0 + row)*CC + c8*8 + 4) = a1;
    }
    // xhatT [c][m], coalesced 256B runs per c
    #pragma unroll
    for (int i = 0; i < 8; ++i) {
        int u = t + 256*i;               // 2048 units = 128 c x 16 key-octets
        int c = u >> 4, k8 = u & 15;
        ushort4 o0, o1;
        o0.x = tile[(k8*8+0)*132 + c]; o0.y = tile[(k8*8+1)*132 + c];
        o0.z = tile[(k8*8+2)*132 + c]; o0.w = tile[(k8*8+3)*132 + c];
        o1.x = tile[(k8*8+4)*132 + c]; o1.y = tile[(k8*8+5)*132 + c];
        o1.z = tile[(k8*8+6)*132 + c]; o1.w = tile[(k8*8+7)*132 + c];
        *(ushort4*)(xhatT + (size_t)c*MM + kb0 + k8*8) = o0;
        *(ushort4*)(xhatT + (size_t)c*MM + kb0 + k8*8 + 4) = o1;
    }
}

// ---------------- query prep: q2 = (l2norm(f)@Kw + kb)@Kw^T * log2e, a = f@W1 ---------
__global__ __launch_bounds__(256) void query_prep_kernel(
    const float* __restrict__ feat, const float* __restrict__ keyw,
    const float* __restrict__ keyb, const float* __restrict__ msgw,
    const int* __restrict__ qrank,
    unsigned short* __restrict__ q2, float* __restrict__ a)
{
    __shared__ float fl[4][128], t1[4][128];
    const int t = threadIdx.x;
    const int w = t >> 6;
    const int lane = t & 63;
    const int b = blockIdx.x*4 + w;
    const int j0 = lane, j1 = lane + 64;
    float f0 = feat[b*CC + j0], f1 = feat[b*CC + j1];
    fl[w][j0] = f0; fl[w][j1] = f1;
    float s = f0*f0 + f1*f1;
    #pragma unroll
    for (int m2 = 1; m2 < 64; m2 <<= 1) s += __shfl_xor(s, m2, 64);
    float invn = 1.0f / fmaxf(sqrtf(s), 1e-12f);
    __syncthreads();
    float g0 = 0.f, g1 = 0.f, a0 = 0.f, a1 = 0.f;
    for (int i = 0; i < 128; ++i) {
        float x = fl[w][i];
        g0 = fmaf(x, keyw[i*128 + j0], g0);
        g1 = fmaf(x, keyw[i*128 + j1], g1);
        a0 = fmaf(x, msgw[i*128 + j0], a0);
        a1 = fmaf(x, msgw[i*128 + j1], a1);
    }
    t1[w][j0] = g0*invn + keyb[j0];
    t1[w][j1] = g1*invn + keyb[j1];
    a[b*CC + j0] = a0;
    a[b*CC + j1] = a1;
    __syncthreads();
    float q0 = 0.f, q1 = 0.f;
    for (int c2 = 0; c2 < 128; ++c2) {
        float u = t1[w][c2];
        q0 = fmaf(u, keyw[j0*128 + c2], q0);
        q1 = fmaf(u, keyw[j1*128 + c2], q1);
    }
    const float LOG2E = 1.4426950408889634f;
    int rb = qrank[b];
    q2[rb*CC + j0] = f2bf(q0 * LOG2E);
    q2[rb*CC + j1] = f2bf(q1 * LOG2E);
}

// ---------------- flash attention: quadrant-split waves -------------------------------
// wave w -> (qhalf = w&1, khalf = w>>1) owns a 32q x 32key quadrant of the 64x64 tile.
__global__ __launch_bounds__(256, 2) void attn_kernel(
    const unsigned short* __restrict__ xhat,
    const unsigned short* __restrict__ xhatT,
    const unsigned short* __restrict__ q2,
    const float* __restrict__ seed_s,
    const float* __restrict__ mst_s,
    const float* __restrict__ y_s,
    unsigned short* __restrict__ Upart,
    float* __restrict__ lpart,
    float* __restrict__ wypart)
{
    __shared__ __align__(16) char pool[32768];          // K [64][128]sw + VT [128][64]sw; reused as f32 scratch
    __shared__ __align__(16) unsigned short P_lds[4][1280]; // per-wave [32 q][40] bf16
    __shared__ float mst_lds[64];
    __shared__ float yf_lds[64];
    __shared__ float lw_lds[2][64];
    __shared__ int ntiles_s;

    const int tid = threadIdx.x;
    const int w = tid >> 6;
    const int lane = tid & 63;
    const int g = lane >> 4;
    const int l15 = lane & 15;
    const int qh = w & 1;
    const int kh = w >> 1;

    // triangle id -> (qb, chunk): heavy (chunk<=qb) cells first
    int qb, chunk;
    {
        int id = blockIdx.x;
        if (id < NTRI) {
            int q = 0, base = 0;
            while (id >= base + q + 1) { base += q + 1; ++q; }
            qb = q; chunk = id - base;
        } else {
            int k = id - NTRI;
            int q = 0;
            while (k >= (NQB - 1) - q) { k -= (NQB - 1) - q; ++q; }
            qb = q; chunk = q + 1 + k;
        }
    }

    const float maxseed = seed_s[qb*64 + 63];
    if (tid < 64) {
        float tm = 3.0e38f;
        if (tid < KCHUNK/64)
            tm = (float)bucket_of(mst_s[(size_t)(chunk*(KCHUNK/64) + tid)*64]) * (1.0f/1024.0f);
        unsigned long long act = __ballot(tm <= maxseed);
        if (tid == 0) ntiles_s = 64 - __clzll(act);
    }
    __syncthreads();
    const int ntiles = ntiles_s;
    if (ntiles == 0) return;   // inactive cell: no writes; final's na predicate matches

    // Q fragments: 2 q-subs x 4 c-chunks
    short8 qf[2][4];
    #pragma unroll
    for (int qs = 0; qs < 2; ++qs)
        #pragma unroll
        for (int cs = 0; cs < 4; ++cs)
            qf[qs][cs] = *(const short8*)(q2 + (size_t)(qb*64 + qh*32 + qs*16 + l15)*CC + cs*32 + g*8);

    float seed_r[2][4];
    #pragma unroll
    for (int qs = 0; qs < 2; ++qs)
        #pragma unroll
        for (int r = 0; r < 4; ++r)
            seed_r[qs][r] = seed_s[qb*64 + qh*32 + qs*16 + g*4 + r];

    f32x4 accU[2][8];
    #pragma unroll
    for (int qs = 0; qs < 2; ++qs)
        #pragma unroll
        for (int n = 0; n < 8; ++n) accU[qs][n] = (f32x4)0.f;
    float accl[2][4] = {{0.f,0.f,0.f,0.f},{0.f,0.f,0.f,0.f}};
    float accw[2][4] = {{0.f,0.f,0.f,0.f},{0.f,0.f,0.f,0.f}};

    for (int kt2 = 0; kt2 < ntiles; ++kt2) {
        const int kb0 = chunk*KCHUNK + kt2*64;
        __syncthreads();
        #pragma unroll
        for (int i = 0; i < 4; ++i) {
            int cid = tid + i*256;
            int row = cid >> 4, cc = cid & 15;
            uint4 v = *(const uint4*)(xhat + (size_t)(kb0 + row)*CC + cc*8);
            *(uint4*)(pool + row*256 + ((cc*16) ^ ((row & 7) << 4))) = v;
        }
        #pragma unroll
        for (int i = 0; i < 4; ++i) {
            int cid = tid + i*256;
            int c = cid >> 3, cc = cid & 7;
            uint4 v = *(const uint4*)(xhatT + (size_t)c*MM + kb0 + cc*8);
            *(uint4*)(pool + 16384 + c*128 + ((cc*16) ^ ((c & 7) << 4))) = v;
        }
        if (tid < 64) {
            mst_lds[tid] = mst_s[kb0 + tid];
            yf_lds[tid] = y_s[kb0 + tid];
        }
        __syncthreads();

        // QK^T on this wave's key strip; P kept wave-local
        #pragma unroll
        for (int ks = 0; ks < 2; ++ks) {
            const int key = (kh*2 + ks)*16 + l15;
            f32x4 s0 = (f32x4)0.f, s1 = (f32x4)0.f;
            #pragma unroll
            for (int cs = 0; cs < 4; ++cs) {
                short8 kf = *(const short8*)(pool + key*256 + ((cs*64 + g*16) ^ ((key & 7) << 4)));
                s0 = __builtin_amdgcn_mfma_f32_16x16x32_bf16(qf[0][cs], kf, s0, 0, 0, 0);
                s1 = __builtin_amdgcn_mfma_f32_16x16x32_bf16(qf[1][cs], kf, s1, 0, 0, 0);
            }
            float mstv = mst_lds[key];
            float yv = yf_lds[key];
            #pragma unroll
            for (int r = 0; r < 4; ++r) {
                float p0 = (seed_r[0][r] < mstv) ? 0.f : exp2f(s0[r]);
                float p1 = (seed_r[1][r] < mstv) ? 0.f : exp2f(s1[r]);
                accl[0][r] += p0; accw[0][r] += p0*yv;
                accl[1][r] += p1; accw[1][r] += p1*yv;
                P_lds[w][(g*4 + r)*40 + ks*16 + l15] = f2bf(p0);
                P_lds[w][(16 + g*4 + r)*40 + ks*16 + l15] = f2bf(p1);
            }
        }
        asm volatile("s_waitcnt lgkmcnt(0)" ::: "memory");
        // PV: U[qh-quadrant] += P(strip) @ xhat(strip)
        short8 pa0 = *(const short8*)((const char*)&P_lds[w][0] + l15*80 + g*16);
        short8 pa1 = *(const short8*)((const char*)&P_lds[w][0] + (16 + l15)*80 + g*16);
        #pragma unroll
        for (int n = 0; n < 8; ++n) {
            const int c = n*16 + l15;
            short8 vf = *(const short8*)(pool + 16384 + c*128 + ((kh*64 + g*16) ^ ((c & 7) << 4)));
            accU[0][n] = __builtin_amdgcn_mfma_f32_16x16x32_bf16(pa0, vf, accU[0][n], 0, 0, 0);
            accU[1][n] = __builtin_amdgcn_mfma_f32_16x16x32_bf16(pa1, vf, accU[1][n], 0, 0, 0);
        }
    }

    // ---- cross-wave (khalf) reduction and writeout ----
    __syncthreads();                  // all waves done reading K/VT pool
    float* scr = (float*)pool;        // [64 q][128 c]
    if (kh == 1) {
        #pragma unroll
        for (int qs = 0; qs < 2; ++qs)
            #pragma unroll
            for (int n = 0; n < 8; ++n)
                #pragma unroll
                for (int r = 0; r < 4; ++r)
                    scr[(qh*32 + qs*16 + g*4 + r)*128 + n*16 + l15] = accU[qs][n][r];
        #pragma unroll
        for (int qs = 0; qs < 2; ++qs)
            #pragma unroll
            for (int r = 0; r < 4; ++r) {
                float lv = accl[qs][r], wv = accw[qs][r];
                #pragma unroll
                for (int m2 = 1; m2 < 16; m2 <<= 1) {
                    lv += __shfl_xor(lv, m2, 64);
                    wv += __shfl_xor(wv, m2, 64);
                }
                if (l15 == 0) {
                    lw_lds[0][qh*32 + qs*16 + g*4 + r] = lv;
                    lw_lds[1][qh*32 + qs*16 + g*4 + r] = wv;
                }
            }
    }
    __syncthreads();
    if (kh == 0) {
        const int rbase = (qb*NSPLIT + chunk)*64;
        #pragma unroll
        for (int qs = 0; qs < 2; ++qs) {
            #pragma unroll
            for (int n = 0; n < 8; ++n)
                #pragma unroll
                for (int r = 0; r < 4; ++r) {
                    int q = qh*32 + qs*16 + g*4 + r;
                    float sum = accU[qs][n][r] + scr[q*128 + n*16 + l15];
                    Upart[(size_t)(rbase + q)*CC + n*16 + l15] = f2bf(sum);
                }
            #pragma unroll
            for (int r = 0; r < 4; ++r) {
                float lv = accl[qs][r], wv = accw[qs][r];
                #pragma unroll
                for (int m2 = 1; m2 < 16; m2 <<= 1) {
                    lv += __shfl_xor(lv, m2, 64);
                    wv += __shfl_xor(wv, m2, 64);
                }
                if (l15 == 0) {
                    int q = qh*32 + qs*16 + g*4 + r;
                    lpart[rbase + q] = lv + lw_lds[0][q];
                    wypart[rbase + q] = wv + lw_lds[1][q];
                }
            }
        }
    }
}

// ---------------- fused combine + epilogue MLP ----------------------------------------
__global__ __launch_bounds__(256) void final_kernel(
    const float* __restrict__ feat, const unsigned short* __restrict__ Upart,
    const float* __restrict__ lpart, const float* __restrict__ wypart,
    const float* __restrict__ seed_s, const float* __restrict__ mst_s,
    const float* __restrict__ a, const float* __restrict__ etab,
    const float* __restrict__ msgw, const int* __restrict__ qperm,
    const float* __restrict__ uw1, const float* __restrict__ ub1,
    const float* __restrict__ uw2, const float* __restrict__ ub2,
    float* __restrict__ out)
{
    __shared__ float fl[4][128], t0[4][128], t1l[4][128];
    __shared__ int na_s;
    const int t = threadIdx.x;
    const int w = t >> 6;
    const int lane = t & 63;
    const int b0 = blockIdx.x*4;
    const int qb = b0 >> 6;
    if (t < 64) {
        float maxseed = seed_s[qb*64 + 63];
        float lb = (t < NSPLIT) ? (float)bucket_of(mst_s[(size_t)t*KCHUNK]) * (1.0f/1024.0f) : 3.0e38f;
        unsigned long long act = __ballot(lb <= maxseed);
        if (t == 0) na_s = (int)__popcll(act);
    }
    __syncthreads();
    const int na = na_s;                 // >=1 (mst_s[0] = -1e9 -> bucket 0)
    const int b = b0 + w;                // sorted row
    const int ob = qperm[b];             // original row
    const int rowin = b & 63;
    const int j0 = lane, j1 = lane + 64;
    float f0 = feat[ob*CC + j0], f1 = feat[ob*CC + j1];
    fl[w][j0] = f0; fl[w][j1] = f1;
    // l, wy across active chunks
    float lv = 0.f, wv = 0.f;
    if (lane < na) {
        int o = (qb*NSPLIT + lane)*64 + rowin;
        lv = lpart[o]; wv = wypart[o];
    }
    #pragma unroll
    for (int m2 = 1; m2 < 64; m2 <<= 1) {
        lv += __shfl_xor(lv, m2, 64);
        wv += __shfl_xor(wv, m2, 64);
    }
    // U sums
    float u0 = 0.f, u1 = 0.f;
    for (int j = 0; j < na; ++j) {
        const unsigned short* up = Upart + (size_t)((qb*NSPLIT + j)*64 + rowin)*CC;
        u0 += bf2f(up[j0]); u1 += bf2f(up[j1]);
    }
    t0[w][j0] = u0; t0[w][j1] = u1;
    __syncthreads();
    float linv = 1.0f / lv;
    float s1 = wv / lv;
    float acc0 = 0.f, acc1 = 0.f;
    for (int i = 0; i < 128; ++i) {
        float x = t0[w][i];
        acc0 = fmaf(x, msgw[(128 + i)*128 + j0], acc0);
        acc1 = fmaf(x, msgw[(128 + i)*128 + j1], acc1);
    }
    float mix0 = (1.f - s1)*etab[j0] + s1*etab[128 + j0];
    float mix1 = (1.f - s1)*etab[j1] + s1*etab[128 + j1];
    float hg0 = a[ob*CC + j0] + acc0*linv + mix0;
    float hg1 = a[ob*CC + j1] + acc1*linv + mix1;
    __syncthreads();
    t0[w][j0] = hg0; t0[w][j1] = hg1;
    __syncthreads();
    float h0 = ub1[j0], h1 = ub1[j1];
    for (int i = 0; i < 128; ++i) {
        float xf = fl[w][i];
        float xh = t0[w][i];
        h0 = fmaf(xf, uw1[i*128 + j0], h0);
        h1 = fmaf(xf, uw1[i*128 + j1], h1);
        h0 = fmaf(xh, uw1[(128 + i)*128 + j0], h0);
        h1 = fmaf(xh, uw1[(128 + i)*128 + j1], h1);
    }
    h0 = fmaxf(h0, 0.f); h1 = fmaxf(h1, 0.f);
    t1l[w][j0] = h0; t1l[w][j1] = h1;
    __syncthreads();
    float o0 = ub2[j0], o1 = ub2[j1];
    for (int i = 0; i < 128; ++i) {
        float x = t1l[w][i];
        o0 = fmaf(x, uw2[i*128 + j0], o0);
        o1 = fmaf(x, uw2[i*128 + j1], o1);
    }
    out[ob*CC + j0] = f0 + o0;
    out[ob*CC + j1] = f1 + o1;
}

extern "C" void kernel_launch(void* const* d_in, const int* in_sizes, int n_in,
                              void* d_out, int out_size, void* d_ws, size_t ws_size,
                              hipStream_t stream) {
    (void)in_sizes; (void)n_in; (void)out_size; (void)ws_size;
    const float* feature  = (const float*)d_in[0];
    const float* memory_x = (const float*)d_in[1];
    const int*   memory_y = (const int*)d_in[2];
    const float* seed_t   = (const float*)d_in[3];
    const float* mem_st   = (const float*)d_in[4];
    const float* key_w    = (const float*)d_in[5];
    const float* key_b    = (const float*)d_in[6];
    const float* msg_w    = (const float*)d_in[7];
    const float* msg_b    = (const float*)d_in[8];
    const float* upd_w1   = (const float*)d_in[9];
    const float* upd_b1   = (const float*)d_in[10];
    const float* upd_w2   = (const float*)d_in[11];
    const float* upd_b2   = (const float*)d_in[12];
    const float* y_emb    = (const float*)d_in[13];
    float* out = (float*)d_out;

    // ---- bump-allocated workspace (256B aligned) ----
    char* ws = (char*)d_ws;
    size_t off = 0;
    auto A = [&](size_t bytes) -> char* {
        char* p = ws + off;
        off += (bytes + 255) & ~(size_t)255;
        return p;
    };
    unsigned short* xhat  = (unsigned short*)A((size_t)MM*CC*2);        // 16 MB
    unsigned short* xhatT = (unsigned short*)A((size_t)MM*CC*2);        // 16 MB
    unsigned short* q2    = (unsigned short*)A((size_t)BQ*CC*2);        // 512 KB
    float* a      = (float*)A((size_t)BQ*CC*4);                         // 1 MB
    float* etab   = (float*)A(2*CC*4);
    float* lpart  = (float*)A((size_t)NQB*NSPLIT*64*4);                 // 256 KB
    float* wypart = (float*)A((size_t)NQB*NSPLIT*64*4);                 // 256 KB
    int*   dperm  = (int*)A((size_t)MM*4);                              // 256 KB
    float* mst_s  = (float*)A((size_t)MM*4);                            // 256 KB
    float* y_s    = (float*)A((size_t)MM*4);                            // 256 KB
    unsigned int* histT = (unsigned int*)A((size_t)NBUCKET*256*4);      // 1 MB
    unsigned int* btot  = (unsigned int*)A(NBUCKET*4);
    unsigned int* gbase = (unsigned int*)A(NBUCKET*4);
    int*   qperm  = (int*)A(BQ*4);
    int*   qrank  = (int*)A(BQ*4);
    float* seed_s = (float*)A(BQ*4);
    unsigned short* Upart = (unsigned short*)A((size_t)BQ*NSPLIT*CC*2); // 16 MB

    qrank_kernel<<<BQ/8, 256, 0, stream>>>(seed_t, qperm, qrank, seed_s);
    sort_hist_kernel<<<MM/256, 256, 0, stream>>>(mem_st, histT);
    sort_scanA_kernel<<<NBUCKET, 64, 0, stream>>>(histT, btot);
    sort_scanB_kernel<<<1, 1024, 0, stream>>>(btot, gbase);
    sort_scatter_kernel<<<MM/256, 256, 0, stream>>>(mem_st, histT, gbase, dperm, mst_s);
    mem_norm_kernel<<<MM/128, 256, 0, stream>>>(memory_x, dperm, memory_y, xhat, xhatT, y_s);
    query_prep_kernel<<<BQ/4, 256, 0, stream>>>(feature, key_w, key_b, msg_w, qrank, q2, a);
    etab_kernel<<<1, 128, 0, stream>>>(msg_w, msg_b, y_emb, etab);
    attn_kernel<<<NQB*NSPLIT, 256, 0, stream>>>(xhat, xhatT, q2, seed_s, mst_s, y_s,
                                                Upart, lpart, wypart);
    final_kernel<<<BQ/4, 256, 0, stream>>>(feature, Upart, lpart, wypart, seed_s, mst_s,
                                           a, etab, msg_w, qperm,
                                           upd_w1, upd_b1, upd_w2, upd_b2, out);
}

// Round 6
// 214.838 us; speedup vs baseline: 1.4339x; 1.0527x over previous
//
#include <hip/hip_runtime.h>

#define BQ 2048
#define MM 65536
#define CC 128
#define NSPLIT 32
#define KCHUNK (MM/NSPLIT)
#define NQB (BQ/64)
#define NBUCKET 1024
#define NTRI ((NQB*(NQB+1))/2)   // 528 lower-triangle cells

typedef short short8 __attribute__((ext_vector_type(8)));
typedef float f32x4 __attribute__((ext_vector_type(4)));
typedef unsigned int u32;

__device__ __forceinline__ unsigned short f2bf(float x) {
    unsigned int u = __builtin_bit_cast(unsigned int, x);
    u = (u + 0x7FFFu + ((u >> 16) & 1u)) >> 16;
    return (unsigned short)u;
}
__device__ __forceinline__ float bf2f(unsigned short u) {
    return __builtin_bit_cast(float, (unsigned int)u << 16);
}
__device__ __forceinline__ int bucket_of(float v) {
    return (int)fminf(fmaxf(v * 1024.0f, 0.0f), 1023.0f);
}
// async global->LDS, 16B per lane; LDS dest = wave-uniform base + lane*16
__device__ __forceinline__ void gload16(const void* g, void* l) {
    __builtin_amdgcn_global_load_lds(
        (const __attribute__((address_space(1))) u32*)g,
        (__attribute__((address_space(3))) u32*)l, 16, 0, 0);
}

// ---------------- exact query rank by seed_time (parallel, deterministic) -------------
__global__ __launch_bounds__(256) void qrank_kernel(
    const float* __restrict__ seed, int* __restrict__ qperm,
    int* __restrict__ qrank, float* __restrict__ seed_s)
{
    int t = threadIdx.x;
    int q = blockIdx.x*8 + (t >> 5);
    int l32 = t & 31;
    float v = seed[q];
    int r = 0;
    for (int seg = 0; seg < 64; ++seg) {
        int j = seg*32 + l32;
        float u = seed[j];
        r += (u < v) || (u == v && j < q);
    }
    #pragma unroll
    for (int m2 = 1; m2 < 32; m2 <<= 1) r += __shfl_xor(r, m2, 32);
    if (l32 == 0) { qperm[r] = q; qrank[q] = r; seed_s[r] = v; }
}

// ---------------- counting sort of memory keys by mst ---------------------------------
__global__ __launch_bounds__(256) void sort_hist_kernel(
    const float* __restrict__ mst, unsigned int* __restrict__ histT)
{
    __shared__ unsigned int h[NBUCKET];
    int t = threadIdx.x, b = blockIdx.x;
    #pragma unroll
    for (int j = t; j < NBUCKET; j += 256) h[j] = 0;
    __syncthreads();
    int bin = bucket_of(mst[b*256 + t]);
    atomicAdd(&h[bin], 1u);
    __syncthreads();
    #pragma unroll
    for (int j = t; j < NBUCKET; j += 256) histT[(size_t)j*256 + b] = h[j];
}

__global__ __launch_bounds__(64) void sort_scanA_kernel(
    unsigned int* __restrict__ histT, unsigned int* __restrict__ btot)
{
    int j = blockIdx.x;
    int t = threadIdx.x;
    uint4 v = *(uint4*)(histT + (size_t)j*256 + t*4);
    unsigned int s0 = v.x, s1 = v.y, s2 = v.z, s3 = v.w;
    unsigned int tsum = s0 + s1 + s2 + s3;
    unsigned int inc = tsum;
    #pragma unroll
    for (int off = 1; off < 64; off <<= 1) {
        unsigned int n = __shfl_up(inc, off, 64);
        if (t >= off) inc += n;
    }
    unsigned int ex = inc - tsum;
    uint4 o;
    o.x = ex; o.y = ex + s0; o.z = ex + s0 + s1; o.w = ex + s0 + s1 + s2;
    *(uint4*)(histT + (size_t)j*256 + t*4) = o;
    if (t == 63) btot[j] = inc;
}

__global__ __launch_bounds__(1024) void sort_scanB_kernel(
    const unsigned int* __restrict__ btot, unsigned int* __restrict__ gbase)
{
    __shared__ unsigned int sc[NBUCKET];
    int j = threadIdx.x;
    unsigned int tot = btot[j];
    sc[j] = tot;
    __syncthreads();
    for (int off = 1; off < NBUCKET; off <<= 1) {
        unsigned int y = (j >= off) ? sc[j - off] : 0u;
        __syncthreads();
        sc[j] += y;
        __syncthreads();
    }
    gbase[j] = sc[j] - tot;
}

__global__ __launch_bounds__(256) void sort_scatter_kernel(
    const float* __restrict__ mst, const unsigned int* __restrict__ histT,
    const unsigned int* __restrict__ gbase,
    int* __restrict__ dperm, float* __restrict__ mst_s)
{
    __shared__ int bins[256];
    int t = threadIdx.x, b = blockIdx.x;
    int i = b*256 + t;
    float v = mst[i];
    int bin = bucket_of(v);
    bins[t] = bin;
    __syncthreads();
    int pos = 0;
    for (int j = 0; j < t; ++j) pos += (bins[j] == bin);
    unsigned int dest = gbase[bin] + histT[(size_t)bin*256 + b] + pos;
    dperm[dest] = i;
    mst_s[dest] = v;
}

// ---------------- memory l2norm (gathered) -> xhat + xhatT, both coalesced ------------
__global__ __launch_bounds__(256) void mem_norm_kernel(
    const float* __restrict__ mx, const int* __restrict__ dperm,
    const int* __restrict__ memy,
    unsigned short* __restrict__ xhat, unsigned short* __restrict__ xhatT,
    float* __restrict__ y_s)
{
    __shared__ __align__(16) unsigned short tile[128*132];  // bf16, stride 132
    __shared__ float rs[128];
    __shared__ float invn[128];
    __shared__ int operm[128];
    const int t = threadIdx.x;
    const int kb0 = blockIdx.x * 128;

    if (t < 128) operm[t] = dperm[kb0 + t];
    __syncthreads();
    if (t < 128) y_s[kb0 + t] = (float)memy[operm[t]];

    float4 vals[16];
    #pragma unroll
    for (int i = 0; i < 16; ++i) {
        int f4 = t + 256*i;              // 4096 float4s = 128 rows x 32
        int row = f4 >> 5, col4 = f4 & 31;
        float4 v = *(const float4*)(mx + (size_t)operm[row]*CC + col4*4);
        vals[i] = v;
        float s = v.x*v.x + v.y*v.y + v.z*v.z + v.w*v.w;
        #pragma unroll
        for (int m2 = 1; m2 < 32; m2 <<= 1) s += __shfl_xor(s, m2, 64);
        if ((t & 31) == 0) rs[row] = s;
    }
    __syncthreads();
    if (t < 128) invn[t] = 1.0f / fmaxf(sqrtf(rs[t]), 1e-12f);
    __syncthreads();
    #pragma unroll
    for (int i = 0; i < 16; ++i) {
        int f4 = t + 256*i;
        int row = f4 >> 5, col4 = f4 & 31;
        float sc = invn[row];
        float4 v = vals[i];
        ushort4 o;
        o.x = f2bf(v.x*sc); o.y = f2bf(v.y*sc); o.z = f2bf(v.z*sc); o.w = f2bf(v.w*sc);
        *(ushort4*)&tile[row*132 + col4*4] = o;
    }
    __syncthreads();
    // xhat row-major, coalesced
    #pragma unroll
    for (int i = 0; i < 8; ++i) {
        int u = t + 256*i;               // 2048 units = 128 rows x 16
        int row = u >> 4, c8 = u & 15;
        ushort4 a0 = *(ushort4*)&tile[row*132 + c8*8];
        ushort4 a1 = *(ushort4*)&tile[row*132 + c8*8 + 4];
        *(ushort4*)(xhat + (size_t)(kb0 + row)*CC + c8*8) = a0;
        *(ushort4*)(xhat + (size_t)(kb0 + row)*CC + c8*8 + 4) = a1;
    }
    // xhatT [c][m], coalesced 256B runs per c
    #pragma unroll
    for (int i = 0; i < 8; ++i) {
        int u = t + 256*i;               // 2048 units = 128 c x 16 key-octets
        int c = u >> 4, k8 = u & 15;
        ushort4 o0, o1;
        o0.x = tile[(k8*8+0)*132 + c]; o0.y = tile[(k8*8+1)*132 + c];
        o0.z = tile[(k8*8+2)*132 + c]; o0.w = tile[(k8*8+3)*132 + c];
        o1.x = tile[(k8*8+4)*132 + c]; o1.y = tile[(k8*8+5)*132 + c];
        o1.z = tile[(k8*8+6)*132 + c]; o1.w = tile[(k8*8+7)*132 + c];
        *(ushort4*)(xhatT + (size_t)c*MM + kb0 + k8*8) = o0;
        *(ushort4*)(xhatT + (size_t)c*MM + kb0 + k8*8 + 4) = o1;
    }
}

// ---------------- query prep (+ etab fold): q2 = (l2norm(f)@Kw + kb)@Kw^T * log2e -----
__global__ __launch_bounds__(256) void query_prep_kernel(
    const float* __restrict__ feat, const float* __restrict__ keyw,
    const float* __restrict__ keyb, const float* __restrict__ msgw,
    const float* __restrict__ msgb, const float* __restrict__ yemb,
    const int* __restrict__ qrank,
    unsigned short* __restrict__ q2, float* __restrict__ a,
    float* __restrict__ etab)
{
    __shared__ float fl[4][128], t1[4][128];
    const int t = threadIdx.x;
    if (blockIdx.x == BQ/4) {           // folded etab: etab = y_emb@W3 + msg_b
        if (t < 128) {
            float acc0 = msgb[t], acc1 = msgb[t];
            for (int c2 = 0; c2 < 128; ++c2) {
                float w3 = msgw[(256 + c2)*128 + t];
                acc0 = fmaf(yemb[c2], w3, acc0);
                acc1 = fmaf(yemb[128 + c2], w3, acc1);
            }
            etab[t] = acc0;
            etab[128 + t] = acc1;
        }
        return;
    }
    const int w = t >> 6;
    const int lane = t & 63;
    const int b = blockIdx.x*4 + w;
    const int j0 = lane, j1 = lane + 64;
    float f0 = feat[b*CC + j0], f1 = feat[b*CC + j1];
    fl[w][j0] = f0; fl[w][j1] = f1;
    float s = f0*f0 + f1*f1;
    #pragma unroll
    for (int m2 = 1; m2 < 64; m2 <<= 1) s += __shfl_xor(s, m2, 64);
    float invn = 1.0f / fmaxf(sqrtf(s), 1e-12f);
    __syncthreads();
    float g0 = 0.f, g1 = 0.f, a0 = 0.f, a1 = 0.f;
    for (int i = 0; i < 128; ++i) {
        float x = fl[w][i];
        g0 = fmaf(x, keyw[i*128 + j0], g0);
        g1 = fmaf(x, keyw[i*128 + j1], g1);
        a0 = fmaf(x, msgw[i*128 + j0], a0);
        a1 = fmaf(x, msgw[i*128 + j1], a1);
    }
    t1[w][j0] = g0*invn + keyb[j0];
    t1[w][j1] = g1*invn + keyb[j1];
    a[b*CC + j0] = a0;
    a[b*CC + j1] = a1;
    __syncthreads();
    float q0 = 0.f, q1 = 0.f;
    for (int c2 = 0; c2 < 128; ++c2) {
        float u = t1[w][c2];
        q0 = fmaf(u, keyw[j0*128 + c2], q0);
        q1 = fmaf(u, keyw[j1*128 + c2], q1);
    }
    const float LOG2E = 1.4426950408889634f;
    int rb = qrank[b];
    q2[rb*CC + j0] = f2bf(q0 * LOG2E);
    q2[rb*CC + j1] = f2bf(q1 * LOG2E);
}

// ---------------- flash attention: dbuf async staging, counted vmcnt ------------------
// wave w owns a 16q strip x all 64 keys (round-4 shape, empirically best).
// LDS pool[buf]: K [64 rows][16 cc x 16B] (cc pre-swizzled: holds xhat[row][(cc^(row&7))*8])
//                VT at +16384: [128 c][8 cc x 16B] (cc pre-swizzled by c&7).
__global__ __launch_bounds__(256, 2) void attn_kernel(
    const unsigned short* __restrict__ xhat,
    const unsigned short* __restrict__ xhatT,
    const unsigned short* __restrict__ q2,
    const float* __restrict__ seed_s,
    const float* __restrict__ mst_s,
    const float* __restrict__ y_s,
    unsigned short* __restrict__ Upart,
    float* __restrict__ lpart,
    float* __restrict__ wypart)
{
    __shared__ __align__(16) char pool[2][32768];
    __shared__ __align__(16) unsigned short P_lds[4][16*72];

    const int tid = threadIdx.x;
    const int w = tid >> 6;
    const int lane = tid & 63;
    const int g = lane >> 4;
    const int l15 = lane & 15;

    // triangle id -> (qb, chunk): heavy (chunk<=qb) cells first
    int qb, chunk;
    {
        int id = blockIdx.x;
        if (id < NTRI) {
            int q = 0, base = 0;
            while (id >= base + q + 1) { base += q + 1; ++q; }
            qb = q; chunk = id - base;
        } else {
            int k = id - NTRI;
            int q = 0;
            while (k >= (NQB - 1) - q) { k -= (NQB - 1) - q; ++q; }
            qb = q; chunk = q + 1 + k;
        }
    }

    // ntiles: per-wave ballot (no LDS, no barrier); all waves compute the same value
    const float maxseed = seed_s[qb*64 + 63];
    int ntiles;
    {
        float tm = 3.0e38f;
        if (lane < KCHUNK/64)
            tm = (float)bucket_of(mst_s[(size_t)(chunk*(KCHUNK/64) + lane)*64]) * (1.0f/1024.0f);
        unsigned long long act = __ballot(tm <= maxseed);
        ntiles = 64 - __clzll(act);
    }
    if (ntiles == 0) return;   // no writes; final's na predicate matches exactly

    const int qrow0 = qb*64 + w*16;
    short8 qf[4];
    #pragma unroll
    for (int cs = 0; cs < 4; ++cs)
        qf[cs] = *(const short8*)(q2 + (size_t)(qrow0 + l15)*CC + cs*32 + g*8);
    float seed_r[4];
    #pragma unroll
    for (int r = 0; r < 4; ++r) seed_r[r] = seed_s[qrow0 + g*4 + r];

    f32x4 accU[8];
    #pragma unroll
    for (int n = 0; n < 8; ++n) accU[n] = (f32x4)0.f;
    float accl[4] = {0.f, 0.f, 0.f, 0.f};
    float accw[4] = {0.f, 0.f, 0.f, 0.f};

    // async stage of one 64-key tile into pool[buf] (8 x global_load_lds per wave)
    auto stage = [&](int buf, int kb0) {
        #pragma unroll
        for (int i = 0; i < 4; ++i) {
            int row = w*16 + i*4 + (lane >> 4);
            gload16(xhat + (size_t)(kb0 + row)*CC + (((lane & 15) ^ (row & 7)) << 3),
                    &pool[buf][w*4096 + i*1024]);
        }
        #pragma unroll
        for (int i = 0; i < 4; ++i) {
            int c = w*32 + i*8 + (lane >> 3);
            gload16(xhatT + (size_t)c*MM + kb0 + (((lane & 7) ^ (c & 7)) << 3),
                    &pool[buf][16384 + w*4096 + i*1024]);
        }
    };

    const int cbase = chunk*KCHUNK;
    stage(0, cbase);               // prologue: tile 0 in flight
    int cur = 0;

    for (int kt2 = 0; kt2 < ntiles; ++kt2) {
        const int kb0 = cbase + kt2*64;
        // per-lane mask/label regs for tile t (latency hidden under barrier+QK)
        float mv[4], yv4[4];
        #pragma unroll
        for (int s2 = 0; s2 < 4; ++s2) {
            mv[s2]  = mst_s[kb0 + s2*16 + l15];
            yv4[s2] = y_s[kb0 + s2*16 + l15];
        }
        const bool hasnext = (kt2 + 1 < ntiles);
        if (hasnext) {
            stage(cur ^ 1, kb0 + 64);                       // issue next tile
            asm volatile("s_waitcnt vmcnt(16)" ::: "memory"); // tile-t stage done; 16 newest (msty+next) in flight
        } else {
            asm volatile("s_waitcnt vmcnt(8)" ::: "memory");  // tile-t stage done; msty may remain
        }
        __builtin_amdgcn_s_barrier();                       // all waves' tile-t LDS ready
        __builtin_amdgcn_sched_barrier(0);

        const char* Kp = &pool[cur][0];
        const char* Vp = &pool[cur][16384];

        #pragma unroll
        for (int sub = 0; sub < 4; ++sub) {
            f32x4 s = (f32x4)0.f;
            const int key = sub*16 + l15;
            #pragma unroll
            for (int cs = 0; cs < 4; ++cs) {
                short8 kf = *(const short8*)(Kp + key*256 + ((cs*64 + g*16) ^ ((key & 7) << 4)));
                s = __builtin_amdgcn_mfma_f32_16x16x32_bf16(qf[cs], kf, s, 0, 0, 0);
            }
            float mstv = mv[sub];
            float yvv = yv4[sub];
            #pragma unroll
            for (int r = 0; r < 4; ++r) {
                float p = (seed_r[r] < mstv) ? 0.f : exp2f(s[r]);
                accl[r] += p;
                accw[r] += p * yvv;
                P_lds[w][(g*4 + r)*72 + key] = f2bf(p);
            }
        }
        asm volatile("s_waitcnt lgkmcnt(0)" ::: "memory");  // P writes visible (wave-local)
        __builtin_amdgcn_sched_barrier(0);
        #pragma unroll
        for (int kk = 0; kk < 2; ++kk) {
            short8 pa = *(const short8*)((const char*)&P_lds[w][0] + l15*144 + kk*64 + g*16);
            #pragma unroll
            for (int n = 0; n < 8; ++n) {
                const int c = n*16 + l15;
                short8 vf = *(const short8*)(Vp + c*128 + ((kk*64 + g*16) ^ ((c & 7) << 4)));
                accU[n] = __builtin_amdgcn_mfma_f32_16x16x32_bf16(pa, vf, accU[n], 0, 0, 0);
            }
        }
        __builtin_amdgcn_s_barrier();                       // all reads of pool[cur] done before reuse
        __builtin_amdgcn_sched_barrier(0);
        cur ^= 1;
    }

    // epilogue: per-wave partial writes (16q strip each)
    const int rbase = (qb*NSPLIT + chunk)*64 + w*16;
    #pragma unroll
    for (int r = 0; r < 4; ++r) {
        float lv = accl[r], wv = accw[r];
        #pragma unroll
        for (int m2 = 1; m2 < 16; m2 <<= 1) {
            lv += __shfl_xor(lv, m2, 64);
            wv += __shfl_xor(wv, m2, 64);
        }
        if (l15 == 0) {
            lpart[rbase + g*4 + r] = lv;
            wypart[rbase + g*4 + r] = wv;
        }
    }
    #pragma unroll
    for (int n = 0; n < 8; ++n) {
        #pragma unroll
        for (int r = 0; r < 4; ++r)
            Upart[(size_t)(rbase + g*4 + r)*CC + n*16 + l15] = f2bf(accU[n][r]);
    }
}

// ---------------- fused combine + epilogue MLP ----------------------------------------
__global__ __launch_bounds__(256) void final_kernel(
    const float* __restrict__ feat, const unsigned short* __restrict__ Upart,
    const float* __restrict__ lpart, const float* __restrict__ wypart,
    const float* __restrict__ seed_s, const float* __restrict__ mst_s,
    const float* __restrict__ a, const float* __restrict__ etab,
    const float* __restrict__ msgw, const int* __restrict__ qperm,
    const float* __restrict__ uw1, const float* __restrict__ ub1,
    const float* __restrict__ uw2, const float* __restrict__ ub2,
    float* __restrict__ out)
{
    __shared__ float fl[4][128], t0[4][128], t1l[4][128];
    __shared__ int na_s;
    const int t = threadIdx.x;
    const int w = t >> 6;
    const int lane = t & 63;
    const int b0 = blockIdx.x*4;
    const int qb = b0 >> 6;
    if (t < 64) {
        float maxseed = seed_s[qb*64 + 63];
        float lb = (t < NSPLIT) ? (float)bucket_of(mst_s[(size_t)t*KCHUNK]) * (1.0f/1024.0f) : 3.0e38f;
        unsigned long long act = __ballot(lb <= maxseed);
        if (t == 0) na_s = (int)__popcll(act);
    }
    __syncthreads();
    const int na = na_s;                 // >=1 (mst_s[0] = -1e9 -> bucket 0)
    const int b = b0 + w;                // sorted row
    const int ob = qperm[b];             // original row
    const int rowin = b & 63;
    const int j0 = lane, j1 = lane + 64;
    float f0 = feat[ob*CC + j0], f1 = feat[ob*CC + j1];
    fl[w][j0] = f0; fl[w][j1] = f1;
    float lv = 0.f, wv = 0.f;
    if (lane < na) {
        int o = (qb*NSPLIT + lane)*64 + rowin;
        lv = lpart[o]; wv = wypart[o];
    }
    #pragma unroll
    for (int m2 = 1; m2 < 64; m2 <<= 1) {
        lv += __shfl_xor(lv, m2, 64);
        wv += __shfl_xor(wv, m2, 64);
    }
    float u0 = 0.f, u1 = 0.f;
    for (int j = 0; j < na; ++j) {
        const unsigned short* up = Upart + (size_t)((qb*NSPLIT + j)*64 + rowin)*CC;
        u0 += bf2f(up[j0]); u1 += bf2f(up[j1]);
    }
    t0[w][j0] = u0; t0[w][j1] = u1;
    __syncthreads();
    float linv = 1.0f / lv;
    float s1 = wv / lv;
    float acc0 = 0.f, acc1 = 0.f;
    for (int i = 0; i < 128; ++i) {
        float x = t0[w][i];
        acc0 = fmaf(x, msgw[(128 + i)*128 + j0], acc0);
        acc1 = fmaf(x, msgw[(128 + i)*128 + j1], acc1);
    }
    float mix0 = (1.f - s1)*etab[j0] + s1*etab[128 + j0];
    float mix1 = (1.f - s1)*etab[j1] + s1*etab[128 + j1];
    float hg0 = a[ob*CC + j0] + acc0*linv + mix0;
    float hg1 = a[ob*CC + j1] + acc1*linv + mix1;
    __syncthreads();
    t0[w][j0] = hg0; t0[w][j1] = hg1;
    __syncthreads();
    float h0 = ub1[j0], h1 = ub1[j1];
    for (int i = 0; i < 128; ++i) {
        float xf = fl[w][i];
        float xh = t0[w][i];
        h0 = fmaf(xf, uw1[i*128 + j0], h0);
        h1 = fmaf(xf, uw1[i*128 + j1], h1);
        h0 = fmaf(xh, uw1[(128 + i)*128 + j0], h0);
        h1 = fmaf(xh, uw1[(128 + i)*128 + j1], h1);
    }
    h0 = fmaxf(h0, 0.f); h1 = fmaxf(h1, 0.f);
    t1l[w][j0] = h0; t1l[w][j1] = h1;
    __syncthreads();
    float o0 = ub2[j0], o1 = ub2[j1];
    for (int i = 0; i < 128; ++i) {
        float x = t1l[w][i];
        o0 = fmaf(x, uw2[i*128 + j0], o0);
        o1 = fmaf(x, uw2[i*128 + j1], o1);
    }
    out[ob*CC + j0] = f0 + o0;
    out[ob*CC + j1] = f1 + o1;
}

extern "C" void kernel_launch(void* const* d_in, const int* in_sizes, int n_in,
                              void* d_out, int out_size, void* d_ws, size_t ws_size,
                              hipStream_t stream) {
    (void)in_sizes; (void)n_in; (void)out_size; (void)ws_size;
    const float* feature  = (const float*)d_in[0];
    const float* memory_x = (const float*)d_in[1];
    const int*   memory_y = (const int*)d_in[2];
    const float* seed_t   = (const float*)d_in[3];
    const float* mem_st   = (const float*)d_in[4];
    const float* key_w    = (const float*)d_in[5];
    const float* key_b    = (const float*)d_in[6];
    const float* msg_w    = (const float*)d_in[7];
    const float* msg_b    = (const float*)d_in[8];
    const float* upd_w1   = (const float*)d_in[9];
    const float* upd_b1   = (const float*)d_in[10];
    const float* upd_w2   = (const float*)d_in[11];
    const float* upd_b2   = (const float*)d_in[12];
    const float* y_emb    = (const float*)d_in[13];
    float* out = (float*)d_out;

    // ---- bump-allocated workspace (256B aligned) ----
    char* ws = (char*)d_ws;
    size_t off = 0;
    auto A = [&](size_t bytes) -> char* {
        char* p = ws + off;
        off += (bytes + 255) & ~(size_t)255;
        return p;
    };
    unsigned short* xhat  = (unsigned short*)A((size_t)MM*CC*2);        // 16 MB
    unsigned short* xhatT = (unsigned short*)A((size_t)MM*CC*2);        // 16 MB
    unsigned short* q2    = (unsigned short*)A((size_t)BQ*CC*2);        // 512 KB
    float* a      = (float*)A((size_t)BQ*CC*4);                         // 1 MB
    float* etab   = (float*)A(2*CC*4);
    float* lpart  = (float*)A((size_t)NQB*NSPLIT*64*4);                 // 256 KB
    float* wypart = (float*)A((size_t)NQB*NSPLIT*64*4);                 // 256 KB
    int*   dperm  = (int*)A((size_t)MM*4);                              // 256 KB
    float* mst_s  = (float*)A((size_t)MM*4);                            // 256 KB
    float* y_s    = (float*)A((size_t)MM*4);                            // 256 KB
    unsigned int* histT = (unsigned int*)A((size_t)NBUCKET*256*4);      // 1 MB
    unsigned int* btot  = (unsigned int*)A(NBUCKET*4);
    unsigned int* gbase = (unsigned int*)A(NBUCKET*4);
    int*   qperm  = (int*)A(BQ*4);
    int*   qrank  = (int*)A(BQ*4);
    float* seed_s = (float*)A(BQ*4);
    unsigned short* Upart = (unsigned short*)A((size_t)BQ*NSPLIT*CC*2); // 16 MB

    qrank_kernel<<<BQ/8, 256, 0, stream>>>(seed_t, qperm, qrank, seed_s);
    sort_hist_kernel<<<MM/256, 256, 0, stream>>>(mem_st, histT);
    sort_scanA_kernel<<<NBUCKET, 64, 0, stream>>>(histT, btot);
    sort_scanB_kernel<<<1, 1024, 0, stream>>>(btot, gbase);
    sort_scatter_kernel<<<MM/256, 256, 0, stream>>>(mem_st, histT, gbase, dperm, mst_s);
    mem_norm_kernel<<<MM/128, 256, 0, stream>>>(memory_x, dperm, memory_y, xhat, xhatT, y_s);
    query_prep_kernel<<<BQ/4 + 1, 256, 0, stream>>>(feature, key_w, key_b, msg_w, msg_b,
                                                    y_emb, qrank, q2, a, etab);
    attn_kernel<<<NQB*NSPLIT, 256, 0, stream>>>(xhat, xhatT, q2, seed_s, mst_s, y_s,
                                                Upart, lpart, wypart);
    final_kernel<<<BQ/4, 256, 0, stream>>>(feature, Upart, lpart, wypart, seed_s, mst_s,
                                           a, etab, msg_w, qperm,
                                           upd_w1, upd_b1, upd_w2, upd_b2, out);
}